// Round 18
// baseline (408.305 us; speedup 1.0000x reference)
//
#include <hip/hip_runtime.h>
#include <hip/hip_bf16.h>

#define DEV __device__ __forceinline__

typedef __attribute__((ext_vector_type(8))) short bf16x8_t;
typedef __attribute__((ext_vector_type(4))) float f32x4_t;

constexpr int cB = 4, cC = 256, cH = 256, cW = 128, cHN = 8, cHS = 32;
constexpr int cM = cB * cH * cW;  // 131072 rows

DEV float bfu(unsigned int b16) { union { unsigned int u; float f; } v; v.u = b16 << 16; return v.f; }
DEV unsigned short f2bb(float f) { union { __hip_bfloat16 h; unsigned short u; } v; v.h = __float2bfloat16(f); return v.u; }
DEV unsigned int pk2(float a, float b) { return (unsigned)f2bb(a) | ((unsigned)f2bb(b) << 16); }

#define GLOAD_LDS16(g, l) \
  __builtin_amdgcn_global_load_lds((const __attribute__((address_space(1))) void*)(g), \
                                   (__attribute__((address_space(3))) void*)(l), 16, 0, 0)

// fast exact-GELU: A&S 7.1.26 erf approximation (max abs err 1.5e-7) — proven absmax 0.031
DEV float gelu_fast(float v) {
  float ax = fabsf(v) * 0.7071067811865475f;
  float t = __builtin_amdgcn_rcpf(1.0f + 0.3275911f * ax);
  float poly = ((((1.061405429f * t - 1.453152027f) * t + 1.421413741f) * t
                 - 0.284496736f) * t + 0.254829592f) * t;
  float e = __expf(-ax * ax);
  float erfv = 1.0f - poly * e;  // erf(|v|/sqrt2)
  float phi = 0.5f + 0.5f * copysignf(erfv, v);
  return v * phi;
}

// ---------------- weight transpose + fp32->bf16 ----------------
__global__ __launch_bounds__(256) void transpose_bf16(const float* __restrict__ src,
                                                      __hip_bfloat16* __restrict__ dst,
                                                      int R, int Ccol) {
  int idx = blockIdx.x * 256 + threadIdx.x;
  if (idx < R * Ccol) {
    int r = idx / Ccol, c = idx - r * Ccol;
    dst[c * R + r] = __float2bfloat16(src[idx]);
  }
}

// transpose for w2 -> fp8 e4m3, scaled x64, with the 256-group k-digit-swap matching
// ffn1_wide's packed stores: within each 256-k group, k -> (k&15)*16 + ((k>>4)&15)
__global__ __launch_bounds__(256) void transpose_perm_fp8(const float* __restrict__ src,
                                                          unsigned char* __restrict__ dst,
                                                          int R, int Ccol) {
  int idx = blockIdx.x * 256 + threadIdx.x;
  if (idx < R * Ccol) {
    int r = idx / Ccol, c = idx - r * Ccol;  // r = k, c = n
    int pk = (r & ~255) | ((r & 15) << 4) | ((r >> 4) & 15);
    int u = __builtin_amdgcn_cvt_pk_fp8_f32(src[idx] * 64.0f, 0.0f, 0, false);
    dst[(size_t)c * R + pk] = (unsigned char)(u & 0xff);
  }
}

// ---------------- RoPE sin/cos table: [w=128][c=16] -> (sin, cos) ----------------
__global__ __launch_bounds__(256) void rope_init(float2* __restrict__ tab) {
  int i = blockIdx.x * 256 + threadIdx.x;  // 2048 entries
  int w = i >> 4, c = i & 15;
  float inv = expf((float)c * -0.28782313662425572f);  // 100^(-c/16)
  float ang = (float)w * inv;
  tab[i] = make_float2(sinf(ang), cosf(ang));
}

// ---------------- MFMA attention: grouped proj + RoPE + softpick + PV ----------------
// one block per (b, h, g); 256 threads = 4 waves. Direct-to-register X fragments,
// fp8 (x16) P/V^T in permuted-k layout (pos = (k&15)*8 + (k>>4)), fp8 PV MFMA.
// No min-waves bound (round 16: (256,4) forced VGPR=48 -> scratch spills, regressed).
constexpr int WQ_OFF = 0, WK_OFF = 2560, WV_OFF = 5120, QS_OFF = 7680, KS_OFF = 17920;
constexpr int VT_OFF = 28160, P_OFF = 0;
constexpr int SMEM_BYTES = 32512;

__global__ __launch_bounds__(256) void attn_mfma(
    const float* __restrict__ left, const float* __restrict__ right,
    const float* __restrict__ qw, const float* __restrict__ kw, const float* __restrict__ vw,
    const float2* __restrict__ rope,
    __hip_bfloat16* __restrict__ att_out)
{
  __shared__ __align__(16) char smem[SMEM_BYTES];

  const int t = threadIdx.x;
  const int g = blockIdx.x & 7;
  const int h = (blockIdx.x >> 3) & 255;
  const int b = blockIdx.x >> 11;
  const size_t HW = (size_t)cH * cW;

  const int lane = t & 63, wid = t >> 6;
  const int c = lane & 15, q4 = lane >> 4;
  const int wbase = wid * 32;
  const f32x4_t zero = {0.f, 0.f, 0.f, 0.f};

  const float* lb = left  + ((size_t)(b * cC + g * cHS) * cH + h) * cW;
  const float* rb = right + ((size_t)(b * cC + g * cHS) * cH + h) * cW;

  // ---- direct-to-register X fragments ----
  bf16x8_t a_xl[2], a_xr[2];
#pragma unroll
  for (int sub = 0; sub < 2; ++sub) {
    int w = wbase + sub * 16 + c;
    float xl[8], xr[8];
#pragma unroll
    for (int e = 0; e < 8; ++e) {
      xl[e] = lb[(size_t)(q4 * 8 + e) * HW + w];
      xr[e] = rb[(size_t)(q4 * 8 + e) * HW + w];
    }
    union { bf16x8_t v; unsigned int u[4]; } ul, ur;
#pragma unroll
    for (int p = 0; p < 4; ++p) {
      ul.u[p] = pk2(xl[2 * p], xl[2 * p + 1]);
      ur.u[p] = pk2(xr[2 * p], xr[2 * p + 1]);
    }
    a_xl[sub] = ul.v;
    a_xr[sub] = ur.v;
  }

  // ---- stage weights (cooperative) ----
  {
    int o = t >> 3, i0 = (t & 7) * 4;
    {
      float4 v4 = *(const float4*)(qw + g * 1024 + t * 4);
      unsigned short* dst = (unsigned short*)(smem + WQ_OFF) + o * 40 + i0;
      *(unsigned int*)(dst) = pk2(v4.x, v4.y); *(unsigned int*)(dst + 2) = pk2(v4.z, v4.w);
    }
    {
      float4 v4 = *(const float4*)(kw + g * 1024 + t * 4);
      unsigned short* dst = (unsigned short*)(smem + WK_OFF) + o * 40 + i0;
      *(unsigned int*)(dst) = pk2(v4.x, v4.y); *(unsigned int*)(dst + 2) = pk2(v4.z, v4.w);
    }
    {
      float4 v4 = *(const float4*)(vw + g * 1024 + t * 4);
      unsigned short* dst = (unsigned short*)(smem + WV_OFF) + o * 40 + i0;
      *(unsigned int*)(dst) = pk2(v4.x, v4.y); *(unsigned int*)(dst + 2) = pk2(v4.z, v4.w);
    }
  }
  __syncthreads();  // B1

  // ---- QK projection (MFMA) + RoPE ----
  f32x4_t qacc[2][2], kacc[2][2];
#pragma unroll
  for (int ot = 0; ot < 2; ++ot) {
    bf16x8_t bq = *(const bf16x8_t*)(smem + WQ_OFF + (ot * 16 + c) * 80 + q4 * 16);
    bf16x8_t bk = *(const bf16x8_t*)(smem + WK_OFF + (ot * 16 + c) * 80 + q4 * 16);
#pragma unroll
    for (int sub = 0; sub < 2; ++sub) {
      qacc[sub][ot] = __builtin_amdgcn_mfma_f32_16x16x32_bf16(a_xl[sub], bq, zero, 0, 0, 0);
      kacc[sub][ot] = __builtin_amdgcn_mfma_f32_16x16x32_bf16(a_xr[sub], bk, zero, 0, 0, 0);
    }
  }
  {
    const float scale = 0.17677669529663687f;  // 1/sqrt(32)
    unsigned short* qsp = (unsigned short*)(smem + QS_OFF);
    unsigned short* ksp = (unsigned short*)(smem + KS_OFF);
#pragma unroll
    for (int sub = 0; sub < 2; ++sub)
#pragma unroll
      for (int r = 0; r < 4; ++r) {
        int w = wbase + sub * 16 + q4 * 4 + r;
        float2 sc = rope[w * 16 + c];
        float sn = sc.x, cs = sc.y;
        float q0 = qacc[sub][0][r], q1 = qacc[sub][1][r];
        qsp[w * 40 + c]      = f2bb((q0 * cs - q1 * sn) * scale);
        qsp[w * 40 + c + 16] = f2bb((q1 * cs + q0 * sn) * scale);
        float k0 = kacc[sub][0][r], k1 = kacc[sub][1][r];
        ksp[w * 40 + c]      = f2bb(k0 * cs - k1 * sn);
        ksp[w * 40 + c + 16] = f2bb(k1 * cs + k0 * sn);
      }
  }
  __syncthreads();  // B2

  // ---- V^T projection; fp8 x16, permuted-k ----
  {
    f32x4_t vacc[2][2];
#pragma unroll
    for (int dt = 0; dt < 2; ++dt) {
      bf16x8_t awv = *(const bf16x8_t*)(smem + WV_OFF + (dt * 16 + c) * 80 + q4 * 16);
#pragma unroll
      for (int sub = 0; sub < 2; ++sub)
        vacc[dt][sub] = __builtin_amdgcn_mfma_f32_16x16x32_bf16(awv, a_xr[sub], zero, 0, 0, 0);
    }
    unsigned char* vtp = (unsigned char*)(smem + VT_OFF);
#pragma unroll
    for (int dt = 0; dt < 2; ++dt)
#pragma unroll
      for (int r = 0; r < 4; ++r) {
        int d = dt * 16 + q4 * 4 + r;
        int u = __builtin_amdgcn_cvt_pk_fp8_f32(vacc[dt][0][r] * 16.0f,
                                                vacc[dt][1][r] * 16.0f, 0, false);
        *(unsigned short*)(vtp + d * 136 + c * 8 + wid * 2) = (unsigned short)(u & 0xffff);
      }
  }

  // ---- S = Q' K'^T (MFMA) ----
  bf16x8_t aq0 = *(const bf16x8_t*)(smem + QS_OFF + (wbase + c) * 80 + q4 * 16);
  bf16x8_t aq1 = *(const bf16x8_t*)(smem + QS_OFF + (wbase + 16 + c) * 80 + q4 * 16);
  f32x4_t sac[2][8];
#pragma unroll
  for (int kt = 0; kt < 8; ++kt) {
    bf16x8_t bk = *(const bf16x8_t*)(smem + KS_OFF + (kt * 16 + c) * 80 + q4 * 16);
    sac[0][kt] = __builtin_amdgcn_mfma_f32_16x16x32_bf16(aq0, bk, zero, 0, 0, 0);
    sac[1][kt] = __builtin_amdgcn_mfma_f32_16x16x32_bf16(aq1, bk, zero, 0, 0, 0);
  }

  // ---- softpick ----
  float dinv_[2][4];
#pragma unroll
  for (int sub = 0; sub < 2; ++sub)
#pragma unroll
    for (int r = 0; r < 4; ++r) {
      float m = sac[sub][0][r];
#pragma unroll
      for (int kt = 1; kt < 8; ++kt) m = fmaxf(m, sac[sub][kt][r]);
      m = fmaxf(m, __shfl_xor(m, 1));
      m = fmaxf(m, __shfl_xor(m, 2));
      m = fmaxf(m, __shfl_xor(m, 4));
      m = fmaxf(m, __shfl_xor(m, 8));
      float em = __expf(-m);
      float ss = 0.f;
#pragma unroll
      for (int kt = 0; kt < 8; ++kt) {
        float e = __expf(sac[sub][kt][r] - m) - em;
        sac[sub][kt][r] = fmaxf(e, 0.f);
        ss += fabsf(e);
      }
      ss += __shfl_xor(ss, 1);
      ss += __shfl_xor(ss, 2);
      ss += __shfl_xor(ss, 4);
      ss += __shfl_xor(ss, 8);
      dinv_[sub][r] = 1.0f / (ss + 1e-6f);
    }
  __syncthreads();  // B3

  // ---- write P fp8 (x16), permuted-k ----
  {
    unsigned char* pp = (unsigned char*)(smem + P_OFF);
#pragma unroll
    for (int sub = 0; sub < 2; ++sub)
#pragma unroll
      for (int r = 0; r < 4; ++r) {
        int w = wbase + sub * 16 + q4 * 4 + r;
        float s16 = dinv_[sub][r] * 16.0f;
        int u0 = __builtin_amdgcn_cvt_pk_fp8_f32(sac[sub][0][r] * s16, sac[sub][1][r] * s16, 0, false);
        u0 = __builtin_amdgcn_cvt_pk_fp8_f32(sac[sub][2][r] * s16, sac[sub][3][r] * s16, u0, true);
        int u1 = __builtin_amdgcn_cvt_pk_fp8_f32(sac[sub][4][r] * s16, sac[sub][5][r] * s16, 0, false);
        u1 = __builtin_amdgcn_cvt_pk_fp8_f32(sac[sub][6][r] * s16, sac[sub][7][r] * s16, u1, true);
        uint2 u; u.x = (unsigned)u0; u.y = (unsigned)u1;
        *(uint2*)(pp + w * 136 + c * 8) = u;
      }
  }

  // ---- PV (fp8 MFMA) ----
  f32x4_t oacc[2][2] = {{zero, zero}, {zero, zero}};
#pragma unroll
  for (int ks = 0; ks < 4; ++ks) {
    long ap0 = *(const long*)(smem + P_OFF + (wbase + c) * 136 + ks * 32 + q4 * 8);
    long ap1 = *(const long*)(smem + P_OFF + (wbase + 16 + c) * 136 + ks * 32 + q4 * 8);
    long bv0 = *(const long*)(smem + VT_OFF + (c) * 136 + ks * 32 + q4 * 8);
    long bv1 = *(const long*)(smem + VT_OFF + (16 + c) * 136 + ks * 32 + q4 * 8);
    oacc[0][0] = __builtin_amdgcn_mfma_f32_16x16x32_fp8_fp8(ap0, bv0, oacc[0][0], 0, 0, 0);
    oacc[0][1] = __builtin_amdgcn_mfma_f32_16x16x32_fp8_fp8(ap0, bv1, oacc[0][1], 0, 0, 0);
    oacc[1][0] = __builtin_amdgcn_mfma_f32_16x16x32_fp8_fp8(ap1, bv0, oacc[1][0], 0, 0, 0);
    oacc[1][1] = __builtin_amdgcn_mfma_f32_16x16x32_fp8_fp8(ap1, bv1, oacc[1][1], 0, 0, 0);
  }
  {
    __hip_bfloat16* ob = att_out + ((size_t)(b * cH + h) * cW) * cC + g * cHS;
#pragma unroll
    for (int sub = 0; sub < 2; ++sub)
#pragma unroll
      for (int dt = 0; dt < 2; ++dt)
#pragma unroll
        for (int r = 0; r < 4; ++r) {
          int w = wbase + sub * 16 + q4 * 4 + r;
          ob[(size_t)w * cC + dt * 16 + c] = __float2bfloat16(oacc[sub][dt][r] * 0.00390625f);
        }
  }
}

// ---------------- ffn1 wide GEMM: hidden(fp8,x64) = gelu(x1 @ w1T^T + b1) ----------------
// BM=128 x BN=256, grid 4096. Grid mapping puts the 4 n-siblings of each A-band on the
// SAME XCD 8 dispatch-ids apart (round 15's nc=id>>10 put them 1024 apart -> L2 evict,
// FETCH 134 MB). Epilogue: 256-group k-digit-swap -> each thread's 16 cols contiguous,
// full-cache-line uint4 stores (16 lanes x 16B = 256B runs).
__global__ __launch_bounds__(256, 2) void ffn1_wide(
    const __hip_bfloat16* __restrict__ A, const __hip_bfloat16* __restrict__ Bt,
    const float* __restrict__ bias, unsigned char* __restrict__ outb)
{
  constexpr int KK = 256, N = 1024;
  __shared__ __align__(16) char smem[73728];  // 3 x (As 8KB + Bs 16KB)
  const int t = threadIdx.x, lane = t & 63, wid = t >> 6;
  const int c = lane & 15, q4 = lane >> 4;
  const int id = blockIdx.x;
  const int xcd = id & 7, k = id >> 3;
  const int nc = k & 3, mbl = k >> 2;           // 4 siblings adjacent (ids 8 apart, same XCD)
  const int m0 = (xcd * 128 + mbl) * 128;       // each XCD owns a contiguous 128-band stripe
  const int n0 = nc * 256;
  const int wr = wid * 32;
  const f32x4_t zero = {0.f, 0.f, 0.f, 0.f};

  f32x4_t acc[2][16];
#pragma unroll
  for (int fi = 0; fi < 2; ++fi)
#pragma unroll
    for (int fj = 0; fj < 16; ++fj) acc[fi][fj] = zero;

  const __hip_bfloat16* Bbase = Bt + (size_t)n0 * KK;

  auto stage = [&](int buf, int k0) {
    char* As = smem + buf * 24576;
    char* Bs = As + 8192;
#pragma unroll
    for (int i = 0; i < 2; ++i) {
      int chunk = (wid * 2 + i);
      int row = chunk * 16 + (lane >> 2);
      int sw = (((lane & 3) ^ ((row >> 1) & 3))) * 8;
      GLOAD_LDS16(A + (size_t)(m0 + row) * KK + k0 + sw, As + chunk * 1024);
    }
#pragma unroll
    for (int i = 0; i < 4; ++i) {
      int chunk = (wid * 4 + i);
      int row = chunk * 16 + (lane >> 2);
      int sw = (((lane & 3) ^ ((row >> 1) & 3))) * 8;
      GLOAD_LDS16(Bbase + (size_t)row * KK + k0 + sw, Bs + chunk * 1024);
    }
  };

  constexpr int NK = KK >> 5;
  stage(0, 0);
  stage(1, 32);
  for (int tt = 0; tt < NK; ++tt) {
    if (tt + 2 < NK) {
      stage((tt + 2) % 3, (tt + 2) << 5);
      asm volatile("s_waitcnt vmcnt(12)" ::: "memory");
    } else if (tt + 1 < NK) {
      asm volatile("s_waitcnt vmcnt(6)" ::: "memory");
    } else {
      asm volatile("s_waitcnt vmcnt(0)" ::: "memory");
    }
    __builtin_amdgcn_s_barrier();
    __builtin_amdgcn_sched_barrier(0);  // pin ds_reads after the rendezvous (rule #18)
    char* As = smem + (tt % 3) * 24576;
    char* Bs = As + 8192;
    int ra0 = wr + c, ra1 = wr + 16 + c;
    bf16x8_t af0 = *(const bf16x8_t*)(As + ra0 * 64 + ((q4 ^ ((ra0 >> 1) & 3)) * 16));
    bf16x8_t af1 = *(const bf16x8_t*)(As + ra1 * 64 + ((q4 ^ ((ra1 >> 1) & 3)) * 16));
#pragma unroll
    for (int fj = 0; fj < 16; ++fj) {
      int rb = fj * 16 + c;
      bf16x8_t bf = *(const bf16x8_t*)(Bs + rb * 64 + ((q4 ^ ((rb >> 1) & 3)) * 16));
      acc[0][fj] = __builtin_amdgcn_mfma_f32_16x16x32_bf16(af0, bf, acc[0][fj], 0, 0, 0);
      acc[1][fj] = __builtin_amdgcn_mfma_f32_16x16x32_bf16(af1, bf, acc[1][fj], 0, 0, 0);
    }
    __builtin_amdgcn_sched_barrier(0);
    __builtin_amdgcn_s_barrier();
  }

  // ---- epilogue: bias + gelu, x64 scale, fp8 digit-swapped full-line stores (8 x uint4) ----
  float bv[16];
#pragma unroll
  for (int fj = 0; fj < 16; ++fj) bv[fj] = bias[n0 + fj * 16 + c];
  unsigned char* obase = outb + (size_t)(m0 + wr + q4 * 4) * N + n0 + c * 16;
#pragma unroll
  for (int fi = 0; fi < 2; ++fi)
#pragma unroll
    for (int r = 0; r < 4; ++r) {
      uint4 u;
      unsigned int* up = (unsigned int*)&u;
#pragma unroll
      for (int p = 0; p < 4; ++p) {
        float v0 = gelu_fast(acc[fi][4 * p + 0][r] + bv[4 * p + 0]) * 64.0f;
        float v1 = gelu_fast(acc[fi][4 * p + 1][r] + bv[4 * p + 1]) * 64.0f;
        float v2 = gelu_fast(acc[fi][4 * p + 2][r] + bv[4 * p + 2]) * 64.0f;
        float v3 = gelu_fast(acc[fi][4 * p + 3][r] + bv[4 * p + 3]) * 64.0f;
        int w = __builtin_amdgcn_cvt_pk_fp8_f32(v0, v1, 0, false);
        w = __builtin_amdgcn_cvt_pk_fp8_f32(v2, v3, w, true);
        up[p] = (unsigned)w;
      }
      *(uint4*)(obase + (size_t)(fi * 16 + r) * N) = u;
    }
}

// ---------------- proj GEMM + left residual + LN1 -> bf16 x1 (bf16 operands) ----------------
__global__ __launch_bounds__(256, 2) void proj_gemm_ln(
    const __hip_bfloat16* __restrict__ A, const __hip_bfloat16* __restrict__ Bt,
    const float* __restrict__ bias, const float* __restrict__ leftres,
    const float* __restrict__ g, const float* __restrict__ be,
    __hip_bfloat16* __restrict__ outp)
{
  constexpr int KK = 256;
  __shared__ __align__(16) char smem[73728];  // 3 x (As 8KB + Bs 16KB)
  const int t = threadIdx.x, lane = t & 63, wid = t >> 6;
  const int c = lane & 15, q4 = lane >> 4;
  const int m0 = blockIdx.x * 128;
  const int wr = wid * 32;
  const f32x4_t zero = {0.f, 0.f, 0.f, 0.f};

  f32x4_t acc[2][16];
#pragma unroll
  for (int fi = 0; fi < 2; ++fi)
#pragma unroll
    for (int fj = 0; fj < 16; ++fj) acc[fi][fj] = zero;

  auto stage = [&](int buf, int k0) {
    char* As = smem + buf * 24576;
    char* Bs = As + 8192;
#pragma unroll
    for (int i = 0; i < 2; ++i) {
      int chunk = (wid * 2 + i);
      int row = chunk * 16 + (lane >> 2);
      int sw = (((lane & 3) ^ ((row >> 1) & 3))) * 8;
      GLOAD_LDS16(A + (size_t)(m0 + row) * KK + k0 + sw, As + chunk * 1024);
    }
#pragma unroll
    for (int i = 0; i < 4; ++i) {
      int chunk = (wid * 4 + i);
      int row = chunk * 16 + (lane >> 2);
      int sw = (((lane & 3) ^ ((row >> 1) & 3))) * 8;
      GLOAD_LDS16(Bt + (size_t)row * KK + k0 + sw, Bs + chunk * 1024);
    }
  };

  constexpr int NK = KK >> 5;
  stage(0, 0);
  stage(1, 32);
  for (int tt = 0; tt < NK; ++tt) {
    if (tt + 2 < NK) {
      stage((tt + 2) % 3, (tt + 2) << 5);
      asm volatile("s_waitcnt vmcnt(12)" ::: "memory");
    } else if (tt + 1 < NK) {
      asm volatile("s_waitcnt vmcnt(6)" ::: "memory");
    } else {
      asm volatile("s_waitcnt vmcnt(0)" ::: "memory");
    }
    __builtin_amdgcn_s_barrier();
    __builtin_amdgcn_sched_barrier(0);
    char* As = smem + (tt % 3) * 24576;
    char* Bs = As + 8192;
    int ra0 = wr + c, ra1 = wr + 16 + c;
    bf16x8_t af0 = *(const bf16x8_t*)(As + ra0 * 64 + ((q4 ^ ((ra0 >> 1) & 3)) * 16));
    bf16x8_t af1 = *(const bf16x8_t*)(As + ra1 * 64 + ((q4 ^ ((ra1 >> 1) & 3)) * 16));
#pragma unroll
    for (int fj = 0; fj < 16; ++fj) {
      int rb = fj * 16 + c;
      bf16x8_t bf = *(const bf16x8_t*)(Bs + rb * 64 + ((q4 ^ ((rb >> 1) & 3)) * 16));
      acc[0][fj] = __builtin_amdgcn_mfma_f32_16x16x32_bf16(af0, bf, acc[0][fj], 0, 0, 0);
      acc[1][fj] = __builtin_amdgcn_mfma_f32_16x16x32_bf16(af1, bf, acc[1][fj], 0, 0, 0);
    }
    __builtin_amdgcn_sched_barrier(0);
    __builtin_amdgcn_s_barrier();
  }

  // ---- epilogue: bias + left^T residual ----
  {
    const int b_ = m0 >> 15, h_ = (m0 >> 7) & 255;
#pragma unroll
    for (int fj = 0; fj < 16; ++fj) {
      int n = fj * 16 + c;
      float bv = bias[n];
#pragma unroll
      for (int fi = 0; fi < 2; ++fi) {
        int w0 = wr + fi * 16 + q4 * 4;
        float4 lr = *(const float4*)(leftres + (((size_t)b_ * 256 + n) * 256 + h_) * 128 + w0);
        float la[4] = {lr.x, lr.y, lr.z, lr.w};
#pragma unroll
        for (int r = 0; r < 4; ++r) acc[fi][fj][r] += bv + la[r];
      }
    }
  }

  // ---- LN1 in-register ----
  float mu[2][4], rs[2][4];
#pragma unroll
  for (int fi = 0; fi < 2; ++fi)
#pragma unroll
    for (int r = 0; r < 4; ++r) {
      float s = 0.f;
#pragma unroll
      for (int fj = 0; fj < 16; ++fj) s += acc[fi][fj][r];
      s += __shfl_xor(s, 1); s += __shfl_xor(s, 2); s += __shfl_xor(s, 4); s += __shfl_xor(s, 8);
      float m_ = s * (1.0f / 256.0f);
      float sq = 0.f;
#pragma unroll
      for (int fj = 0; fj < 16; ++fj) { float d = acc[fi][fj][r] - m_; sq += d * d; }
      sq += __shfl_xor(sq, 1); sq += __shfl_xor(sq, 2); sq += __shfl_xor(sq, 4); sq += __shfl_xor(sq, 8);
      mu[fi][r] = m_;
      rs[fi][r] = rsqrtf(sq * (1.0f / 256.0f) + 1e-5f);
    }
#pragma unroll
  for (int fj = 0; fj < 16; ++fj) {
    int n = fj * 16 + c;
    float gv = g[n], bev = be[n];
#pragma unroll
    for (int fi = 0; fi < 2; ++fi)
#pragma unroll
      for (int r = 0; r < 4; ++r) {
        int row = wr + fi * 16 + q4 * 4 + r;
        outp[(size_t)(m0 + row) * 256 + n] =
            __float2bfloat16((acc[fi][fj][r] - mu[fi][r]) * rs[fi][r] * gv + bev);
      }
  }
}

// ---------------- ffn2 (fp8 x fp8) + b2 + x1 residual + LN2 -> fp32 d_out ----------------
// A = hidden fp8 (x64, 256-group k-perm); Bt = w2T fp8 (x64, same perm). Byte-position
// agnostic to the shared permutation (A/B pair identical global k at identical bytes).
__global__ __launch_bounds__(256, 2) void ffn2_ln(
    const unsigned char* __restrict__ A, const unsigned char* __restrict__ Bt,
    const float* __restrict__ bias, const __hip_bfloat16* __restrict__ resbf,
    const float* __restrict__ g, const float* __restrict__ be,
    float* __restrict__ outp)
{
  constexpr int KK = 1024;
  __shared__ __align__(16) char smem[73728];  // 3 x (As 8KB + Bs 16KB)
  const int t = threadIdx.x, lane = t & 63, wid = t >> 6;
  const int c = lane & 15, q4 = lane >> 4;
  const int m0 = blockIdx.x * 128;
  const int wr = wid * 32;
  const f32x4_t zero = {0.f, 0.f, 0.f, 0.f};

  f32x4_t acc[2][16];
#pragma unroll
  for (int fi = 0; fi < 2; ++fi)
#pragma unroll
    for (int fj = 0; fj < 16; ++fj) acc[fi][fj] = zero;

  auto stage = [&](int buf, int k0) {
    char* As = smem + buf * 24576;
    char* Bs = As + 8192;
#pragma unroll
    for (int i = 0; i < 2; ++i) {
      int chunk = (wid * 2 + i);
      int row = chunk * 16 + (lane >> 2);
      int sw = (((lane & 3) ^ ((row >> 1) & 3))) * 16;  // 16B slots, byte units
      GLOAD_LDS16(A + (size_t)(m0 + row) * KK + k0 + sw, As + chunk * 1024);
    }
#pragma unroll
    for (int i = 0; i < 4; ++i) {
      int chunk = (wid * 4 + i);
      int row = chunk * 16 + (lane >> 2);
      int sw = (((lane & 3) ^ ((row >> 1) & 3))) * 16;
      GLOAD_LDS16(Bt + (size_t)row * KK + k0 + sw, Bs + chunk * 1024);
    }
  };

  constexpr int NK = 16;  // K-steps of 64 fp8
  stage(0, 0);
  stage(1, 64);
  const int sl = (c >> 1) & 3;
  const int koff0 = ((((q4 >> 1)) ^ sl) << 4) | ((q4 & 1) << 3);
  const int koff1 = (((2 | (q4 >> 1)) ^ sl) << 4) | ((q4 & 1) << 3);
  for (int tt = 0; tt < NK; ++tt) {
    if (tt + 2 < NK) {
      stage((tt + 2) % 3, (tt + 2) << 6);
      asm volatile("s_waitcnt vmcnt(12)" ::: "memory");
    } else if (tt + 1 < NK) {
      asm volatile("s_waitcnt vmcnt(6)" ::: "memory");
    } else {
      asm volatile("s_waitcnt vmcnt(0)" ::: "memory");
    }
    __builtin_amdgcn_s_barrier();
    __builtin_amdgcn_sched_barrier(0);
    char* As = smem + (tt % 3) * 24576;
    char* Bs = As + 8192;
    const char* arow0 = As + (wr + c) * 64;
    const char* arow1 = As + (wr + 16 + c) * 64;
    long a00 = *(const long*)(arow0 + koff0);
    long a01 = *(const long*)(arow0 + koff1);
    long a10 = *(const long*)(arow1 + koff0);
    long a11 = *(const long*)(arow1 + koff1);
#pragma unroll
    for (int fj = 0; fj < 16; ++fj) {
      const char* brow = Bs + (fj * 16 + c) * 64;
      long b0 = *(const long*)(brow + koff0);
      long b1 = *(const long*)(brow + koff1);
      acc[0][fj] = __builtin_amdgcn_mfma_f32_16x16x32_fp8_fp8(a00, b0, acc[0][fj], 0, 0, 0);
      acc[0][fj] = __builtin_amdgcn_mfma_f32_16x16x32_fp8_fp8(a01, b1, acc[0][fj], 0, 0, 0);
      acc[1][fj] = __builtin_amdgcn_mfma_f32_16x16x32_fp8_fp8(a10, b0, acc[1][fj], 0, 0, 0);
      acc[1][fj] = __builtin_amdgcn_mfma_f32_16x16x32_fp8_fp8(a11, b1, acc[1][fj], 0, 0, 0);
    }
    __builtin_amdgcn_sched_barrier(0);
    __builtin_amdgcn_s_barrier();
  }

  // ---- epilogue: unscale (2^-12) + b2 + x1 residual ----
#pragma unroll
  for (int fj = 0; fj < 16; ++fj) {
    int n = fj * 16 + c;
    float bv = bias[n];
#pragma unroll
    for (int fi = 0; fi < 2; ++fi)
#pragma unroll
      for (int r = 0; r < 4; ++r) {
        int row = wr + fi * 16 + q4 * 4 + r;
        acc[fi][fj][r] = acc[fi][fj][r] * 0.000244140625f + bv +
                         __bfloat162float(resbf[(size_t)(m0 + row) * 256 + n]);
      }
  }

  // ---- LN2 in-register ----
  float mu[2][4], rs[2][4];
#pragma unroll
  for (int fi = 0; fi < 2; ++fi)
#pragma unroll
    for (int r = 0; r < 4; ++r) {
      float s = 0.f;
#pragma unroll
      for (int fj = 0; fj < 16; ++fj) s += acc[fi][fj][r];
      s += __shfl_xor(s, 1); s += __shfl_xor(s, 2); s += __shfl_xor(s, 4); s += __shfl_xor(s, 8);
      float m_ = s * (1.0f / 256.0f);
      float sq = 0.f;
#pragma unroll
      for (int fj = 0; fj < 16; ++fj) { float d = acc[fi][fj][r] - m_; sq += d * d; }
      sq += __shfl_xor(sq, 1); sq += __shfl_xor(sq, 2); sq += __shfl_xor(sq, 4); sq += __shfl_xor(sq, 8);
      mu[fi][r] = m_;
      rs[fi][r] = rsqrtf(sq * (1.0f / 256.0f) + 1e-5f);
    }
#pragma unroll
  for (int fj = 0; fj < 16; ++fj) {
    int n = fj * 16 + c;
    float gv = g[n], bev = be[n];
#pragma unroll
    for (int fi = 0; fi < 2; ++fi)
#pragma unroll
      for (int r = 0; r < 4; ++r) {
        int row = wr + fi * 16 + q4 * 4 + r;
        outp[(size_t)(m0 + row) * 256 + n] =
            (acc[fi][fj][r] - mu[fi][r]) * rs[fi][r] * gv + bev;
      }
  }
}

extern "C" void kernel_launch(void* const* d_in, const int* in_sizes, int n_in,
                              void* d_out, int out_size, void* d_ws, size_t ws_size,
                              hipStream_t stream) {
  const float* left   = (const float*)d_in[0];
  const float* right  = (const float*)d_in[1];
  const float* qw     = (const float*)d_in[2];
  const float* kw     = (const float*)d_in[3];
  const float* vw     = (const float*)d_in[4];
  const float* proj_w = (const float*)d_in[5];
  const float* proj_b = (const float*)d_in[6];
  const float* ln1_g  = (const float*)d_in[7];
  const float* ln1_b  = (const float*)d_in[8];
  const float* ln2_g  = (const float*)d_in[9];
  const float* ln2_b  = (const float*)d_in[10];
  const float* w1     = (const float*)d_in[11];
  const float* b1     = (const float*)d_in[12];
  const float* w2     = (const float*)d_in[13];
  const float* b2     = (const float*)d_in[14];

  char* ws = (char*)d_ws;
  __hip_bfloat16* att_out = (__hip_bfloat16*)ws;                 // [M,256]  bf16 [0, 67MB)
  __hip_bfloat16* x1      = (__hip_bfloat16*)(ws + 67108864);    // [M,256]  bf16 [67,134MB)
  unsigned char*  hidden  = (unsigned char*)(ws + 134217728);    // [M,1024] fp8  [134,268MB)
  float2*         rope    = (float2*)(ws + 301989888);           // 16KB
  __hip_bfloat16* pwT     = (__hip_bfloat16*)(ws + 402653184);   // [256][256] bf16
  __hip_bfloat16* w1T     = pwT + 65536;                         // [1024][256] bf16
  unsigned char*  w2T     = (unsigned char*)(w1T + 262144);      // [256][1024] fp8, 256-perm, x64

  transpose_bf16<<<256, 256, 0, stream>>>(proj_w, pwT, 256, 256);
  transpose_bf16<<<1024, 256, 0, stream>>>(w1, w1T, 256, 1024);
  transpose_perm_fp8<<<1024, 256, 0, stream>>>(w2, w2T, 1024, 256);
  rope_init<<<8, 256, 0, stream>>>(rope);

  attn_mfma<<<cB * cH * cHN, 256, 0, stream>>>(left, right, qw, kw, vw, rope, att_out);

  // x1 = LN1(att_out @ proj_w + proj_b + left^T)
  proj_gemm_ln<<<cM / 128, 256, 0, stream>>>(att_out, pwT, proj_b, left, ln1_g, ln1_b, x1);
  // hidden(fp8) = gelu(x1 @ w1 + b1) * 64   (wide epilogue, XCD-sibling grid)
  ffn1_wide<<<4096, 256, 0, stream>>>(x1, w1T, b1, hidden);
  // out = LN2(hidden @ w2 / 4096 + b2 + x1)
  ffn2_ln<<<cM / 128, 256, 0, stream>>>(hidden, w2T, b2, x1, ln2_g, ln2_b, (float*)d_out);
}

// Round 19
// 379.045 us; speedup vs baseline: 1.0772x; 1.0772x over previous
//
#include <hip/hip_runtime.h>
#include <hip/hip_bf16.h>

#define DEV __device__ __forceinline__

typedef __attribute__((ext_vector_type(8))) short bf16x8_t;
typedef __attribute__((ext_vector_type(4))) float f32x4_t;

constexpr int cB = 4, cC = 256, cH = 256, cW = 128, cHN = 8, cHS = 32;
constexpr int cM = cB * cH * cW;  // 131072 rows

DEV float bfu(unsigned int b16) { union { unsigned int u; float f; } v; v.u = b16 << 16; return v.f; }
DEV unsigned short f2bb(float f) { union { __hip_bfloat16 h; unsigned short u; } v; v.h = __float2bfloat16(f); return v.u; }
DEV unsigned int pk2(float a, float b) { return (unsigned)f2bb(a) | ((unsigned)f2bb(b) << 16); }

#define GLOAD_LDS16(g, l) \
  __builtin_amdgcn_global_load_lds((const __attribute__((address_space(1))) void*)(g), \
                                   (__attribute__((address_space(3))) void*)(l), 16, 0, 0)

// sigmoid-GELU: x * sigmoid(1.702 x). |err| <= 0.0103 (<=0.003 for |x|<1.5, which covers
// the N(0,0.32^2) hidden pre-act mass); propagated through w2 -> ~0.01 output perturbation.
// ~5 VALU ops vs ~14 for the A&S erf form. Safe now: round 9's failure was the barrier race
// (fixed round 10 via sched_barrier(0) fences, absmax back to 0.03125 with identical numerics).
DEV float gelu_sig(float x) {
  float e = __expf(-1.702f * x);
  return x * __builtin_amdgcn_rcpf(1.0f + e);
}

// ---------------- weight transpose + fp32->bf16 ----------------
__global__ __launch_bounds__(256) void transpose_bf16(const float* __restrict__ src,
                                                      __hip_bfloat16* __restrict__ dst,
                                                      int R, int Ccol) {
  int idx = blockIdx.x * 256 + threadIdx.x;
  if (idx < R * Ccol) {
    int r = idx / Ccol, c = idx - r * Ccol;
    dst[c * R + r] = __float2bfloat16(src[idx]);
  }
}

// transpose for w2 -> fp8 e4m3, scaled x64, with k-permutation matching ffn1's packed stores:
// within each 64-k group, orig k -> pos ((k&15)<<2) | ((k>>4)&3)
__global__ __launch_bounds__(256) void transpose_perm_fp8(const float* __restrict__ src,
                                                          unsigned char* __restrict__ dst,
                                                          int R, int Ccol) {
  int idx = blockIdx.x * 256 + threadIdx.x;
  if (idx < R * Ccol) {
    int r = idx / Ccol, c = idx - r * Ccol;  // r = k, c = n
    int pk = (r & ~63) | ((r & 15) << 2) | ((r >> 4) & 3);
    int u = __builtin_amdgcn_cvt_pk_fp8_f32(src[idx] * 64.0f, 0.0f, 0, false);
    dst[(size_t)c * R + pk] = (unsigned char)(u & 0xff);
  }
}

// ---------------- RoPE sin/cos table: [w=128][c=16] -> (sin, cos) ----------------
__global__ __launch_bounds__(256) void rope_init(float2* __restrict__ tab) {
  int i = blockIdx.x * 256 + threadIdx.x;  // 2048 entries
  int w = i >> 4, c = i & 15;
  float inv = expf((float)c * -0.28782313662425572f);  // 100^(-c/16)
  float ang = (float)w * inv;
  tab[i] = make_float2(sinf(ang), cosf(ang));
}

// ---------------- MFMA attention: grouped proj + RoPE + softpick + PV ----------------
// one block per (b, h, g); 256 threads = 4 waves. Direct-to-register X fragments,
// fp8 (x16) P/V^T in permuted-k layout (pos = (k&15)*8 + (k>>4)), fp8 PV MFMA.
// No min-waves bound (round 16: (256,4) forced VGPR=48 -> scratch spills, regressed).
constexpr int WQ_OFF = 0, WK_OFF = 2560, WV_OFF = 5120, QS_OFF = 7680, KS_OFF = 17920;
constexpr int VT_OFF = 28160, P_OFF = 0;
constexpr int SMEM_BYTES = 32512;

__global__ __launch_bounds__(256) void attn_mfma(
    const float* __restrict__ left, const float* __restrict__ right,
    const float* __restrict__ qw, const float* __restrict__ kw, const float* __restrict__ vw,
    const float2* __restrict__ rope,
    __hip_bfloat16* __restrict__ att_out)
{
  __shared__ __align__(16) char smem[SMEM_BYTES];

  const int t = threadIdx.x;
  const int g = blockIdx.x & 7;
  const int h = (blockIdx.x >> 3) & 255;
  const int b = blockIdx.x >> 11;
  const size_t HW = (size_t)cH * cW;

  const int lane = t & 63, wid = t >> 6;
  const int c = lane & 15, q4 = lane >> 4;
  const int wbase = wid * 32;
  const f32x4_t zero = {0.f, 0.f, 0.f, 0.f};

  const float* lb = left  + ((size_t)(b * cC + g * cHS) * cH + h) * cW;
  const float* rb = right + ((size_t)(b * cC + g * cHS) * cH + h) * cW;

  // ---- direct-to-register X fragments ----
  bf16x8_t a_xl[2], a_xr[2];
#pragma unroll
  for (int sub = 0; sub < 2; ++sub) {
    int w = wbase + sub * 16 + c;
    float xl[8], xr[8];
#pragma unroll
    for (int e = 0; e < 8; ++e) {
      xl[e] = lb[(size_t)(q4 * 8 + e) * HW + w];
      xr[e] = rb[(size_t)(q4 * 8 + e) * HW + w];
    }
    union { bf16x8_t v; unsigned int u[4]; } ul, ur;
#pragma unroll
    for (int p = 0; p < 4; ++p) {
      ul.u[p] = pk2(xl[2 * p], xl[2 * p + 1]);
      ur.u[p] = pk2(xr[2 * p], xr[2 * p + 1]);
    }
    a_xl[sub] = ul.v;
    a_xr[sub] = ur.v;
  }

  // ---- stage weights (cooperative) ----
  {
    int o = t >> 3, i0 = (t & 7) * 4;
    {
      float4 v4 = *(const float4*)(qw + g * 1024 + t * 4);
      unsigned short* dst = (unsigned short*)(smem + WQ_OFF) + o * 40 + i0;
      *(unsigned int*)(dst) = pk2(v4.x, v4.y); *(unsigned int*)(dst + 2) = pk2(v4.z, v4.w);
    }
    {
      float4 v4 = *(const float4*)(kw + g * 1024 + t * 4);
      unsigned short* dst = (unsigned short*)(smem + WK_OFF) + o * 40 + i0;
      *(unsigned int*)(dst) = pk2(v4.x, v4.y); *(unsigned int*)(dst + 2) = pk2(v4.z, v4.w);
    }
    {
      float4 v4 = *(const float4*)(vw + g * 1024 + t * 4);
      unsigned short* dst = (unsigned short*)(smem + WV_OFF) + o * 40 + i0;
      *(unsigned int*)(dst) = pk2(v4.x, v4.y); *(unsigned int*)(dst + 2) = pk2(v4.z, v4.w);
    }
  }
  __syncthreads();  // B1

  // ---- QK projection (MFMA) + RoPE ----
  f32x4_t qacc[2][2], kacc[2][2];
#pragma unroll
  for (int ot = 0; ot < 2; ++ot) {
    bf16x8_t bq = *(const bf16x8_t*)(smem + WQ_OFF + (ot * 16 + c) * 80 + q4 * 16);
    bf16x8_t bk = *(const bf16x8_t*)(smem + WK_OFF + (ot * 16 + c) * 80 + q4 * 16);
#pragma unroll
    for (int sub = 0; sub < 2; ++sub) {
      qacc[sub][ot] = __builtin_amdgcn_mfma_f32_16x16x32_bf16(a_xl[sub], bq, zero, 0, 0, 0);
      kacc[sub][ot] = __builtin_amdgcn_mfma_f32_16x16x32_bf16(a_xr[sub], bk, zero, 0, 0, 0);
    }
  }
  {
    const float scale = 0.17677669529663687f;  // 1/sqrt(32)
    unsigned short* qsp = (unsigned short*)(smem + QS_OFF);
    unsigned short* ksp = (unsigned short*)(smem + KS_OFF);
#pragma unroll
    for (int sub = 0; sub < 2; ++sub)
#pragma unroll
      for (int r = 0; r < 4; ++r) {
        int w = wbase + sub * 16 + q4 * 4 + r;
        float2 sc = rope[w * 16 + c];
        float sn = sc.x, cs = sc.y;
        float q0 = qacc[sub][0][r], q1 = qacc[sub][1][r];
        qsp[w * 40 + c]      = f2bb((q0 * cs - q1 * sn) * scale);
        qsp[w * 40 + c + 16] = f2bb((q1 * cs + q0 * sn) * scale);
        float k0 = kacc[sub][0][r], k1 = kacc[sub][1][r];
        ksp[w * 40 + c]      = f2bb(k0 * cs - k1 * sn);
        ksp[w * 40 + c + 16] = f2bb(k1 * cs + k0 * sn);
      }
  }
  __syncthreads();  // B2

  // ---- V^T projection; fp8 x16, permuted-k ----
  {
    f32x4_t vacc[2][2];
#pragma unroll
    for (int dt = 0; dt < 2; ++dt) {
      bf16x8_t awv = *(const bf16x8_t*)(smem + WV_OFF + (dt * 16 + c) * 80 + q4 * 16);
#pragma unroll
      for (int sub = 0; sub < 2; ++sub)
        vacc[dt][sub] = __builtin_amdgcn_mfma_f32_16x16x32_bf16(awv, a_xr[sub], zero, 0, 0, 0);
    }
    unsigned char* vtp = (unsigned char*)(smem + VT_OFF);
#pragma unroll
    for (int dt = 0; dt < 2; ++dt)
#pragma unroll
      for (int r = 0; r < 4; ++r) {
        int d = dt * 16 + q4 * 4 + r;
        int u = __builtin_amdgcn_cvt_pk_fp8_f32(vacc[dt][0][r] * 16.0f,
                                                vacc[dt][1][r] * 16.0f, 0, false);
        *(unsigned short*)(vtp + d * 136 + c * 8 + wid * 2) = (unsigned short)(u & 0xffff);
      }
  }

  // ---- S = Q' K'^T (MFMA) ----
  bf16x8_t aq0 = *(const bf16x8_t*)(smem + QS_OFF + (wbase + c) * 80 + q4 * 16);
  bf16x8_t aq1 = *(const bf16x8_t*)(smem + QS_OFF + (wbase + 16 + c) * 80 + q4 * 16);
  f32x4_t sac[2][8];
#pragma unroll
  for (int kt = 0; kt < 8; ++kt) {
    bf16x8_t bk = *(const bf16x8_t*)(smem + KS_OFF + (kt * 16 + c) * 80 + q4 * 16);
    sac[0][kt] = __builtin_amdgcn_mfma_f32_16x16x32_bf16(aq0, bk, zero, 0, 0, 0);
    sac[1][kt] = __builtin_amdgcn_mfma_f32_16x16x32_bf16(aq1, bk, zero, 0, 0, 0);
  }

  // ---- softpick ----
  float dinv_[2][4];
#pragma unroll
  for (int sub = 0; sub < 2; ++sub)
#pragma unroll
    for (int r = 0; r < 4; ++r) {
      float m = sac[sub][0][r];
#pragma unroll
      for (int kt = 1; kt < 8; ++kt) m = fmaxf(m, sac[sub][kt][r]);
      m = fmaxf(m, __shfl_xor(m, 1));
      m = fmaxf(m, __shfl_xor(m, 2));
      m = fmaxf(m, __shfl_xor(m, 4));
      m = fmaxf(m, __shfl_xor(m, 8));
      float em = __expf(-m);
      float ss = 0.f;
#pragma unroll
      for (int kt = 0; kt < 8; ++kt) {
        float e = __expf(sac[sub][kt][r] - m) - em;
        sac[sub][kt][r] = fmaxf(e, 0.f);
        ss += fabsf(e);
      }
      ss += __shfl_xor(ss, 1);
      ss += __shfl_xor(ss, 2);
      ss += __shfl_xor(ss, 4);
      ss += __shfl_xor(ss, 8);
      dinv_[sub][r] = 1.0f / (ss + 1e-6f);
    }
  __syncthreads();  // B3

  // ---- write P fp8 (x16), permuted-k ----
  {
    unsigned char* pp = (unsigned char*)(smem + P_OFF);
#pragma unroll
    for (int sub = 0; sub < 2; ++sub)
#pragma unroll
      for (int r = 0; r < 4; ++r) {
        int w = wbase + sub * 16 + q4 * 4 + r;
        float s16 = dinv_[sub][r] * 16.0f;
        int u0 = __builtin_amdgcn_cvt_pk_fp8_f32(sac[sub][0][r] * s16, sac[sub][1][r] * s16, 0, false);
        u0 = __builtin_amdgcn_cvt_pk_fp8_f32(sac[sub][2][r] * s16, sac[sub][3][r] * s16, u0, true);
        int u1 = __builtin_amdgcn_cvt_pk_fp8_f32(sac[sub][4][r] * s16, sac[sub][5][r] * s16, 0, false);
        u1 = __builtin_amdgcn_cvt_pk_fp8_f32(sac[sub][6][r] * s16, sac[sub][7][r] * s16, u1, true);
        uint2 u; u.x = (unsigned)u0; u.y = (unsigned)u1;
        *(uint2*)(pp + w * 136 + c * 8) = u;
      }
  }

  // ---- PV (fp8 MFMA) ----
  f32x4_t oacc[2][2] = {{zero, zero}, {zero, zero}};
#pragma unroll
  for (int ks = 0; ks < 4; ++ks) {
    long ap0 = *(const long*)(smem + P_OFF + (wbase + c) * 136 + ks * 32 + q4 * 8);
    long ap1 = *(const long*)(smem + P_OFF + (wbase + 16 + c) * 136 + ks * 32 + q4 * 8);
    long bv0 = *(const long*)(smem + VT_OFF + (c) * 136 + ks * 32 + q4 * 8);
    long bv1 = *(const long*)(smem + VT_OFF + (16 + c) * 136 + ks * 32 + q4 * 8);
    oacc[0][0] = __builtin_amdgcn_mfma_f32_16x16x32_fp8_fp8(ap0, bv0, oacc[0][0], 0, 0, 0);
    oacc[0][1] = __builtin_amdgcn_mfma_f32_16x16x32_fp8_fp8(ap0, bv1, oacc[0][1], 0, 0, 0);
    oacc[1][0] = __builtin_amdgcn_mfma_f32_16x16x32_fp8_fp8(ap1, bv0, oacc[1][0], 0, 0, 0);
    oacc[1][1] = __builtin_amdgcn_mfma_f32_16x16x32_fp8_fp8(ap1, bv1, oacc[1][1], 0, 0, 0);
  }
  {
    __hip_bfloat16* ob = att_out + ((size_t)(b * cH + h) * cW) * cC + g * cHS;
#pragma unroll
    for (int sub = 0; sub < 2; ++sub)
#pragma unroll
      for (int dt = 0; dt < 2; ++dt)
#pragma unroll
        for (int r = 0; r < 4; ++r) {
          int w = wbase + sub * 16 + q4 * 4 + r;
          ob[(size_t)w * cC + dt * 16 + c] = __float2bfloat16(oacc[sub][dt][r] * 0.00390625f);
        }
  }
}

// ---------------- ffn1 GEMM (round-13 structure): hidden(fp8,x64) = gelu(x1 @ w1T^T + b1) ----
// Epilogue now uses sigmoid-GELU (~5 VALU ops vs ~14): the kernel is VALU-bound (56% busy).
__global__ __launch_bounds__(256) void ffn1_gemm(
    const __hip_bfloat16* __restrict__ A, const __hip_bfloat16* __restrict__ Bt,
    const float* __restrict__ bias, unsigned char* __restrict__ outb)
{
  constexpr int K = 256, N = 1024;
  __shared__ __align__(16) char smem[49152];  // 3 x (As 8KB + Bs 8KB)
  const int t = threadIdx.x;
  const int id = blockIdx.x;
  const int slot = id >> 3;
  const int by = (id & 7) * 128 + (slot >> 3);
  const int bx = slot & 7;
  const int m0 = by * 128, n0 = bx * 128;
  const int lane = t & 63, wid = t >> 6;
  const int r16 = lane & 15, kq = lane >> 4;
  const int wr = (wid >> 1) * 64, wc = (wid & 1) * 64;

  f32x4_t acc[4][4];
#pragma unroll
  for (int fi = 0; fi < 4; ++fi)
#pragma unroll
    for (int fj = 0; fj < 4; ++fj) acc[fi][fj] = {0.f, 0.f, 0.f, 0.f};

  auto stage = [&](int buf, int k0) {
    char* As = smem + buf * 16384;
    char* Bs = As + 8192;
#pragma unroll
    for (int i = 0; i < 2; ++i) {
      int chunk = i * 4 + wid;
      int row = chunk * 16 + (lane >> 2);
      int sw = (((lane & 3) ^ ((row >> 1) & 3))) * 8;
      GLOAD_LDS16(A  + (size_t)(m0 + row) * K + k0 + sw, As + chunk * 1024);
      GLOAD_LDS16(Bt + (size_t)(n0 + row) * K + k0 + sw, Bs + chunk * 1024);
    }
  };

  constexpr int NK = K >> 5;  // 8
  stage(0, 0);
  stage(1, 32);
  for (int tt = 0; tt < NK; ++tt) {
    if (tt + 2 < NK) {
      stage((tt + 2) % 3, (tt + 2) << 5);
      asm volatile("s_waitcnt vmcnt(8)" ::: "memory");
    } else if (tt + 1 < NK) {
      asm volatile("s_waitcnt vmcnt(4)" ::: "memory");
    } else {
      asm volatile("s_waitcnt vmcnt(0)" ::: "memory");
    }
    __builtin_amdgcn_s_barrier();
    __builtin_amdgcn_sched_barrier(0);  // pin ds_reads after the rendezvous (rule #18)
    char* As = smem + (tt % 3) * 16384;
    char* Bs = As + 8192;
    bf16x8_t af[4], bf[4];
#pragma unroll
    for (int fi = 0; fi < 4; ++fi) {
      int rr = wr + fi * 16 + r16;
      af[fi] = *(const bf16x8_t*)(As + rr * 64 + ((kq ^ ((rr >> 1) & 3)) * 16));
    }
#pragma unroll
    for (int fj = 0; fj < 4; ++fj) {
      int rr = wc + fj * 16 + r16;
      bf[fj] = *(const bf16x8_t*)(Bs + rr * 64 + ((kq ^ ((rr >> 1) & 3)) * 16));
    }
#pragma unroll
    for (int fi = 0; fi < 4; ++fi)
#pragma unroll
      for (int fj = 0; fj < 4; ++fj)
        acc[fi][fj] = __builtin_amdgcn_mfma_f32_16x16x32_bf16(af[fi], bf[fj], acc[fi][fj], 0, 0, 0);
    __builtin_amdgcn_sched_barrier(0);
    __builtin_amdgcn_s_barrier();       // WAR
  }

  // ---- epilogue: bias + sigmoid-gelu, x64 scale, fp8 packed permuted stores ----
  float bv[4];
#pragma unroll
  for (int fj = 0; fj < 4; ++fj) bv[fj] = bias[n0 + wc + fj * 16 + r16];
  unsigned char* obase = outb + (size_t)(m0 + wr + kq * 4) * N + n0 + wc + r16 * 4;
#pragma unroll
  for (int fi = 0; fi < 4; ++fi)
#pragma unroll
    for (int r = 0; r < 4; ++r) {
      float v0 = gelu_sig(acc[fi][0][r] + bv[0]) * 64.0f;
      float v1 = gelu_sig(acc[fi][1][r] + bv[1]) * 64.0f;
      float v2 = gelu_sig(acc[fi][2][r] + bv[2]) * 64.0f;
      float v3 = gelu_sig(acc[fi][3][r] + bv[3]) * 64.0f;
      int u = __builtin_amdgcn_cvt_pk_fp8_f32(v0, v1, 0, false);
      u = __builtin_amdgcn_cvt_pk_fp8_f32(v2, v3, u, true);
      *(unsigned int*)(obase + (size_t)(fi * 16 + r) * N) = (unsigned)u;
    }
}

// ---------------- proj GEMM + left residual + LN1 -> bf16 x1 (bf16 operands) ----------------
__global__ __launch_bounds__(256, 2) void proj_gemm_ln(
    const __hip_bfloat16* __restrict__ A, const __hip_bfloat16* __restrict__ Bt,
    const float* __restrict__ bias, const float* __restrict__ leftres,
    const float* __restrict__ g, const float* __restrict__ be,
    __hip_bfloat16* __restrict__ outp)
{
  constexpr int KK = 256;
  __shared__ __align__(16) char smem[73728];  // 3 x (As 8KB + Bs 16KB)
  const int t = threadIdx.x, lane = t & 63, wid = t >> 6;
  const int c = lane & 15, q4 = lane >> 4;
  const int m0 = blockIdx.x * 128;
  const int wr = wid * 32;
  const f32x4_t zero = {0.f, 0.f, 0.f, 0.f};

  f32x4_t acc[2][16];
#pragma unroll
  for (int fi = 0; fi < 2; ++fi)
#pragma unroll
    for (int fj = 0; fj < 16; ++fj) acc[fi][fj] = zero;

  auto stage = [&](int buf, int k0) {
    char* As = smem + buf * 24576;
    char* Bs = As + 8192;
#pragma unroll
    for (int i = 0; i < 2; ++i) {
      int chunk = (wid * 2 + i);
      int row = chunk * 16 + (lane >> 2);
      int sw = (((lane & 3) ^ ((row >> 1) & 3))) * 8;
      GLOAD_LDS16(A + (size_t)(m0 + row) * KK + k0 + sw, As + chunk * 1024);
    }
#pragma unroll
    for (int i = 0; i < 4; ++i) {
      int chunk = (wid * 4 + i);
      int row = chunk * 16 + (lane >> 2);
      int sw = (((lane & 3) ^ ((row >> 1) & 3))) * 8;
      GLOAD_LDS16(Bt + (size_t)row * KK + k0 + sw, Bs + chunk * 1024);
    }
  };

  constexpr int NK = KK >> 5;
  stage(0, 0);
  stage(1, 32);
  for (int tt = 0; tt < NK; ++tt) {
    if (tt + 2 < NK) {
      stage((tt + 2) % 3, (tt + 2) << 5);
      asm volatile("s_waitcnt vmcnt(12)" ::: "memory");
    } else if (tt + 1 < NK) {
      asm volatile("s_waitcnt vmcnt(6)" ::: "memory");
    } else {
      asm volatile("s_waitcnt vmcnt(0)" ::: "memory");
    }
    __builtin_amdgcn_s_barrier();
    __builtin_amdgcn_sched_barrier(0);
    char* As = smem + (tt % 3) * 24576;
    char* Bs = As + 8192;
    int ra0 = wr + c, ra1 = wr + 16 + c;
    bf16x8_t af0 = *(const bf16x8_t*)(As + ra0 * 64 + ((q4 ^ ((ra0 >> 1) & 3)) * 16));
    bf16x8_t af1 = *(const bf16x8_t*)(As + ra1 * 64 + ((q4 ^ ((ra1 >> 1) & 3)) * 16));
#pragma unroll
    for (int fj = 0; fj < 16; ++fj) {
      int rb = fj * 16 + c;
      bf16x8_t bf = *(const bf16x8_t*)(Bs + rb * 64 + ((q4 ^ ((rb >> 1) & 3)) * 16));
      acc[0][fj] = __builtin_amdgcn_mfma_f32_16x16x32_bf16(af0, bf, acc[0][fj], 0, 0, 0);
      acc[1][fj] = __builtin_amdgcn_mfma_f32_16x16x32_bf16(af1, bf, acc[1][fj], 0, 0, 0);
    }
    __builtin_amdgcn_sched_barrier(0);
    __builtin_amdgcn_s_barrier();
  }

  // ---- epilogue: bias + left^T residual ----
  {
    const int b_ = m0 >> 15, h_ = (m0 >> 7) & 255;
#pragma unroll
    for (int fj = 0; fj < 16; ++fj) {
      int n = fj * 16 + c;
      float bv = bias[n];
#pragma unroll
      for (int fi = 0; fi < 2; ++fi) {
        int w0 = wr + fi * 16 + q4 * 4;
        float4 lr = *(const float4*)(leftres + (((size_t)b_ * 256 + n) * 256 + h_) * 128 + w0);
        float la[4] = {lr.x, lr.y, lr.z, lr.w};
#pragma unroll
        for (int r = 0; r < 4; ++r) acc[fi][fj][r] += bv + la[r];
      }
    }
  }

  // ---- LN1 in-register ----
  float mu[2][4], rs[2][4];
#pragma unroll
  for (int fi = 0; fi < 2; ++fi)
#pragma unroll
    for (int r = 0; r < 4; ++r) {
      float s = 0.f;
#pragma unroll
      for (int fj = 0; fj < 16; ++fj) s += acc[fi][fj][r];
      s += __shfl_xor(s, 1); s += __shfl_xor(s, 2); s += __shfl_xor(s, 4); s += __shfl_xor(s, 8);
      float m_ = s * (1.0f / 256.0f);
      float sq = 0.f;
#pragma unroll
      for (int fj = 0; fj < 16; ++fj) { float d = acc[fi][fj][r] - m_; sq += d * d; }
      sq += __shfl_xor(sq, 1); sq += __shfl_xor(sq, 2); sq += __shfl_xor(sq, 4); sq += __shfl_xor(sq, 8);
      mu[fi][r] = m_;
      rs[fi][r] = rsqrtf(sq * (1.0f / 256.0f) + 1e-5f);
    }
#pragma unroll
  for (int fj = 0; fj < 16; ++fj) {
    int n = fj * 16 + c;
    float gv = g[n], bev = be[n];
#pragma unroll
    for (int fi = 0; fi < 2; ++fi)
#pragma unroll
      for (int r = 0; r < 4; ++r) {
        int row = wr + fi * 16 + q4 * 4 + r;
        outp[(size_t)(m0 + row) * 256 + n] =
            __float2bfloat16((acc[fi][fj][r] - mu[fi][r]) * rs[fi][r] * gv + bev);
      }
  }
}

// ---------------- ffn2 (fp8 x fp8) + b2 + x1 residual + LN2 -> fp32 d_out ----------------
__global__ __launch_bounds__(256, 2) void ffn2_ln(
    const unsigned char* __restrict__ A, const unsigned char* __restrict__ Bt,
    const float* __restrict__ bias, const __hip_bfloat16* __restrict__ resbf,
    const float* __restrict__ g, const float* __restrict__ be,
    float* __restrict__ outp)
{
  constexpr int KK = 1024;
  __shared__ __align__(16) char smem[73728];  // 3 x (As 8KB + Bs 16KB)
  const int t = threadIdx.x, lane = t & 63, wid = t >> 6;
  const int c = lane & 15, q4 = lane >> 4;
  const int m0 = blockIdx.x * 128;
  const int wr = wid * 32;
  const f32x4_t zero = {0.f, 0.f, 0.f, 0.f};

  f32x4_t acc[2][16];
#pragma unroll
  for (int fi = 0; fi < 2; ++fi)
#pragma unroll
    for (int fj = 0; fj < 16; ++fj) acc[fi][fj] = zero;

  auto stage = [&](int buf, int k0) {
    char* As = smem + buf * 24576;
    char* Bs = As + 8192;
#pragma unroll
    for (int i = 0; i < 2; ++i) {
      int chunk = (wid * 2 + i);
      int row = chunk * 16 + (lane >> 2);
      int sw = (((lane & 3) ^ ((row >> 1) & 3))) * 16;  // 16B slots, byte units
      GLOAD_LDS16(A + (size_t)(m0 + row) * KK + k0 + sw, As + chunk * 1024);
    }
#pragma unroll
    for (int i = 0; i < 4; ++i) {
      int chunk = (wid * 4 + i);
      int row = chunk * 16 + (lane >> 2);
      int sw = (((lane & 3) ^ ((row >> 1) & 3))) * 16;
      GLOAD_LDS16(Bt + (size_t)row * KK + k0 + sw, Bs + chunk * 1024);
    }
  };

  constexpr int NK = 16;  // K-steps of 64 fp8
  stage(0, 0);
  stage(1, 64);
  const int sl = (c >> 1) & 3;
  const int koff0 = ((((q4 >> 1)) ^ sl) << 4) | ((q4 & 1) << 3);
  const int koff1 = (((2 | (q4 >> 1)) ^ sl) << 4) | ((q4 & 1) << 3);
  for (int tt = 0; tt < NK; ++tt) {
    if (tt + 2 < NK) {
      stage((tt + 2) % 3, (tt + 2) << 6);
      asm volatile("s_waitcnt vmcnt(12)" ::: "memory");
    } else if (tt + 1 < NK) {
      asm volatile("s_waitcnt vmcnt(6)" ::: "memory");
    } else {
      asm volatile("s_waitcnt vmcnt(0)" ::: "memory");
    }
    __builtin_amdgcn_s_barrier();
    __builtin_amdgcn_sched_barrier(0);
    char* As = smem + (tt % 3) * 24576;
    char* Bs = As + 8192;
    const char* arow0 = As + (wr + c) * 64;
    const char* arow1 = As + (wr + 16 + c) * 64;
    long a00 = *(const long*)(arow0 + koff0);
    long a01 = *(const long*)(arow0 + koff1);
    long a10 = *(const long*)(arow1 + koff0);
    long a11 = *(const long*)(arow1 + koff1);
#pragma unroll
    for (int fj = 0; fj < 16; ++fj) {
      const char* brow = Bs + (fj * 16 + c) * 64;
      long b0 = *(const long*)(brow + koff0);
      long b1 = *(const long*)(brow + koff1);
      acc[0][fj] = __builtin_amdgcn_mfma_f32_16x16x32_fp8_fp8(a00, b0, acc[0][fj], 0, 0, 0);
      acc[0][fj] = __builtin_amdgcn_mfma_f32_16x16x32_fp8_fp8(a01, b1, acc[0][fj], 0, 0, 0);
      acc[1][fj] = __builtin_amdgcn_mfma_f32_16x16x32_fp8_fp8(a10, b0, acc[1][fj], 0, 0, 0);
      acc[1][fj] = __builtin_amdgcn_mfma_f32_16x16x32_fp8_fp8(a11, b1, acc[1][fj], 0, 0, 0);
    }
    __builtin_amdgcn_sched_barrier(0);
    __builtin_amdgcn_s_barrier();
  }

  // ---- epilogue: unscale (2^-12) + b2 + x1 residual ----
#pragma unroll
  for (int fj = 0; fj < 16; ++fj) {
    int n = fj * 16 + c;
    float bv = bias[n];
#pragma unroll
    for (int fi = 0; fi < 2; ++fi)
#pragma unroll
      for (int r = 0; r < 4; ++r) {
        int row = wr + fi * 16 + q4 * 4 + r;
        acc[fi][fj][r] = acc[fi][fj][r] * 0.000244140625f + bv +
                         __bfloat162float(resbf[(size_t)(m0 + row) * 256 + n]);
      }
  }

  // ---- LN2 in-register ----
  float mu[2][4], rs[2][4];
#pragma unroll
  for (int fi = 0; fi < 2; ++fi)
#pragma unroll
    for (int r = 0; r < 4; ++r) {
      float s = 0.f;
#pragma unroll
      for (int fj = 0; fj < 16; ++fj) s += acc[fi][fj][r];
      s += __shfl_xor(s, 1); s += __shfl_xor(s, 2); s += __shfl_xor(s, 4); s += __shfl_xor(s, 8);
      float m_ = s * (1.0f / 256.0f);
      float sq = 0.f;
#pragma unroll
      for (int fj = 0; fj < 16; ++fj) { float d = acc[fi][fj][r] - m_; sq += d * d; }
      sq += __shfl_xor(sq, 1); sq += __shfl_xor(sq, 2); sq += __shfl_xor(sq, 4); sq += __shfl_xor(sq, 8);
      mu[fi][r] = m_;
      rs[fi][r] = rsqrtf(sq * (1.0f / 256.0f) + 1e-5f);
    }
#pragma unroll
  for (int fj = 0; fj < 16; ++fj) {
    int n = fj * 16 + c;
    float gv = g[n], bev = be[n];
#pragma unroll
    for (int fi = 0; fi < 2; ++fi)
#pragma unroll
      for (int r = 0; r < 4; ++r) {
        int row = wr + fi * 16 + q4 * 4 + r;
        outp[(size_t)(m0 + row) * 256 + n] =
            (acc[fi][fj][r] - mu[fi][r]) * rs[fi][r] * gv + bev;
      }
  }
}

extern "C" void kernel_launch(void* const* d_in, const int* in_sizes, int n_in,
                              void* d_out, int out_size, void* d_ws, size_t ws_size,
                              hipStream_t stream) {
  const float* left   = (const float*)d_in[0];
  const float* right  = (const float*)d_in[1];
  const float* qw     = (const float*)d_in[2];
  const float* kw     = (const float*)d_in[3];
  const float* vw     = (const float*)d_in[4];
  const float* proj_w = (const float*)d_in[5];
  const float* proj_b = (const float*)d_in[6];
  const float* ln1_g  = (const float*)d_in[7];
  const float* ln1_b  = (const float*)d_in[8];
  const float* ln2_g  = (const float*)d_in[9];
  const float* ln2_b  = (const float*)d_in[10];
  const float* w1     = (const float*)d_in[11];
  const float* b1     = (const float*)d_in[12];
  const float* w2     = (const float*)d_in[13];
  const float* b2     = (const float*)d_in[14];

  char* ws = (char*)d_ws;
  __hip_bfloat16* att_out = (__hip_bfloat16*)ws;                 // [M,256]  bf16 [0, 67MB)
  __hip_bfloat16* x1      = (__hip_bfloat16*)(ws + 67108864);    // [M,256]  bf16 [67,134MB)
  unsigned char*  hidden  = (unsigned char*)(ws + 134217728);    // [M,1024] fp8  [134,268MB)
  float2*         rope    = (float2*)(ws + 301989888);           // 16KB
  __hip_bfloat16* pwT     = (__hip_bfloat16*)(ws + 402653184);   // [256][256] bf16
  __hip_bfloat16* w1T     = pwT + 65536;                         // [1024][256] bf16
  unsigned char*  w2T     = (unsigned char*)(w1T + 262144);      // [256][1024] fp8, k-perm, x64

  transpose_bf16<<<256, 256, 0, stream>>>(proj_w, pwT, 256, 256);
  transpose_bf16<<<1024, 256, 0, stream>>>(w1, w1T, 256, 1024);
  transpose_perm_fp8<<<1024, 256, 0, stream>>>(w2, w2T, 1024, 256);
  rope_init<<<8, 256, 0, stream>>>(rope);

  attn_mfma<<<cB * cH * cHN, 256, 0, stream>>>(left, right, qw, kw, vw, rope, att_out);

  // x1 = LN1(att_out @ proj_w + proj_b + left^T)
  proj_gemm_ln<<<cM / 128, 256, 0, stream>>>(att_out, pwT, proj_b, left, ln1_g, ln1_b, x1);
  // hidden(fp8) = gelu(x1 @ w1 + b1) * 64   (sigmoid-gelu epilogue)
  ffn1_gemm<<<8192, 256, 0, stream>>>(x1, w1T, b1, hidden);
  // out = LN2(hidden @ w2 / 4096 + b2 + x1)
  ffn2_ln<<<cM / 128, 256, 0, stream>>>(hidden, w2T, b2, x1, ln2_g, ln2_b, (float*)d_out);
}

// Round 20
// 367.626 us; speedup vs baseline: 1.1107x; 1.0311x over previous
//
#include <hip/hip_runtime.h>
#include <hip/hip_bf16.h>

#define DEV __device__ __forceinline__

typedef __attribute__((ext_vector_type(8))) short bf16x8_t;
typedef __attribute__((ext_vector_type(4))) float f32x4_t;

constexpr int cB = 4, cC = 256, cH = 256, cW = 128, cHN = 8, cHS = 32;
constexpr int cM = cB * cH * cW;  // 131072 rows

DEV float bfu(unsigned int b16) { union { unsigned int u; float f; } v; v.u = b16 << 16; return v.f; }
DEV unsigned int fbits(float f) { union { float f; unsigned int u; } v; v.f = f; return v.u; }
// exact RNE (used on one-time weight paths)
DEV unsigned short f2bb(float f) { union { __hip_bfloat16 h; unsigned short u; } v; v.h = __float2bfloat16(f); return v.u; }
DEV unsigned int pk2(float a, float b) { return (unsigned)f2bb(a) | ((unsigned)f2bb(b) << 16); }
// truncating bf16 (1-2 VALU ops vs ~5 for RNE); <=1 ulp bf16 error — used on hot paths
DEV unsigned short f2bbt(float f) { return (unsigned short)(fbits(f) >> 16); }
DEV unsigned int pk2t(float a, float b) { return (fbits(a) >> 16) | (fbits(b) & 0xffff0000u); }

#define GLOAD_LDS16(g, l) \
  __builtin_amdgcn_global_load_lds((const __attribute__((address_space(1))) void*)(g), \
                                   (__attribute__((address_space(3))) void*)(l), 16, 0, 0)

// sigmoid-GELU: x * sigmoid(1.702 x). |err| <= 0.0103; ~5 VALU ops. (round-19 proven)
DEV float gelu_sig(float x) {
  float e = __expf(-1.702f * x);
  return x * __builtin_amdgcn_rcpf(1.0f + e);
}

// ---------------- weight transpose + fp32->bf16 ----------------
__global__ __launch_bounds__(256) void transpose_bf16(const float* __restrict__ src,
                                                      __hip_bfloat16* __restrict__ dst,
                                                      int R, int Ccol) {
  int idx = blockIdx.x * 256 + threadIdx.x;
  if (idx < R * Ccol) {
    int r = idx / Ccol, c = idx - r * Ccol;
    dst[c * R + r] = __float2bfloat16(src[idx]);
  }
}

// transpose for w2 -> fp8 e4m3, scaled x64, with k-permutation matching ffn1's packed stores:
// within each 64-k group, orig k -> pos ((k&15)<<2) | ((k>>4)&3)
__global__ __launch_bounds__(256) void transpose_perm_fp8(const float* __restrict__ src,
                                                          unsigned char* __restrict__ dst,
                                                          int R, int Ccol) {
  int idx = blockIdx.x * 256 + threadIdx.x;
  if (idx < R * Ccol) {
    int r = idx / Ccol, c = idx - r * Ccol;  // r = k, c = n
    int pk = (r & ~63) | ((r & 15) << 2) | ((r >> 4) & 3);
    int u = __builtin_amdgcn_cvt_pk_fp8_f32(src[idx] * 64.0f, 0.0f, 0, false);
    dst[(size_t)c * R + pk] = (unsigned char)(u & 0xff);
  }
}

// ---------------- RoPE sin/cos table: [w=128][c=16] -> (sin, cos) ----------------
__global__ __launch_bounds__(256) void rope_init(float2* __restrict__ tab) {
  int i = blockIdx.x * 256 + threadIdx.x;  // 2048 entries
  int w = i >> 4, c = i & 15;
  float inv = expf((float)c * -0.28782313662425572f);  // 100^(-c/16)
  float ang = (float)w * inv;
  tab[i] = make_float2(sinf(ang), cosf(ang));
}

// ---------------- MFMA attention: grouped proj + RoPE + softpick + PV ----------------
// one block per (b, h, g); 256 threads = 4 waves. Direct-to-register X fragments,
// fp8 (x16) P/V^T in permuted-k layout (pos = (k&15)*8 + (k>>4)), fp8 PV MFMA.
// Hot bf16 conversions use TRUNCATION (f2bbt/pk2t): kernel is VALU-bound (50% busy),
// and RNE sequences were ~500 extra VALU ops/thread.
constexpr int WQ_OFF = 0, WK_OFF = 2560, WV_OFF = 5120, QS_OFF = 7680, KS_OFF = 17920;
constexpr int VT_OFF = 28160, P_OFF = 0;
constexpr int SMEM_BYTES = 32512;

__global__ __launch_bounds__(256) void attn_mfma(
    const float* __restrict__ left, const float* __restrict__ right,
    const float* __restrict__ qw, const float* __restrict__ kw, const float* __restrict__ vw,
    const float2* __restrict__ rope,
    __hip_bfloat16* __restrict__ att_out)
{
  __shared__ __align__(16) char smem[SMEM_BYTES];

  const int t = threadIdx.x;
  const int g = blockIdx.x & 7;
  const int h = (blockIdx.x >> 3) & 255;
  const int b = blockIdx.x >> 11;
  const size_t HW = (size_t)cH * cW;

  const int lane = t & 63, wid = t >> 6;
  const int c = lane & 15, q4 = lane >> 4;
  const int wbase = wid * 32;
  const f32x4_t zero = {0.f, 0.f, 0.f, 0.f};

  const float* lb = left  + ((size_t)(b * cC + g * cHS) * cH + h) * cW;
  const float* rb = right + ((size_t)(b * cC + g * cHS) * cH + h) * cW;

  // ---- direct-to-register X fragments (truncating pack) ----
  bf16x8_t a_xl[2], a_xr[2];
#pragma unroll
  for (int sub = 0; sub < 2; ++sub) {
    int w = wbase + sub * 16 + c;
    float xl[8], xr[8];
#pragma unroll
    for (int e = 0; e < 8; ++e) {
      xl[e] = lb[(size_t)(q4 * 8 + e) * HW + w];
      xr[e] = rb[(size_t)(q4 * 8 + e) * HW + w];
    }
    union { bf16x8_t v; unsigned int u[4]; } ul, ur;
#pragma unroll
    for (int p = 0; p < 4; ++p) {
      ul.u[p] = pk2t(xl[2 * p], xl[2 * p + 1]);
      ur.u[p] = pk2t(xr[2 * p], xr[2 * p + 1]);
    }
    a_xl[sub] = ul.v;
    a_xr[sub] = ur.v;
  }

  // ---- stage weights (cooperative; exact RNE, negligible cost) ----
  {
    int o = t >> 3, i0 = (t & 7) * 4;
    {
      float4 v4 = *(const float4*)(qw + g * 1024 + t * 4);
      unsigned short* dst = (unsigned short*)(smem + WQ_OFF) + o * 40 + i0;
      *(unsigned int*)(dst) = pk2(v4.x, v4.y); *(unsigned int*)(dst + 2) = pk2(v4.z, v4.w);
    }
    {
      float4 v4 = *(const float4*)(kw + g * 1024 + t * 4);
      unsigned short* dst = (unsigned short*)(smem + WK_OFF) + o * 40 + i0;
      *(unsigned int*)(dst) = pk2(v4.x, v4.y); *(unsigned int*)(dst + 2) = pk2(v4.z, v4.w);
    }
    {
      float4 v4 = *(const float4*)(vw + g * 1024 + t * 4);
      unsigned short* dst = (unsigned short*)(smem + WV_OFF) + o * 40 + i0;
      *(unsigned int*)(dst) = pk2(v4.x, v4.y); *(unsigned int*)(dst + 2) = pk2(v4.z, v4.w);
    }
  }
  __syncthreads();  // B1

  // ---- QK projection (MFMA) + RoPE (truncating stores) ----
  f32x4_t qacc[2][2], kacc[2][2];
#pragma unroll
  for (int ot = 0; ot < 2; ++ot) {
    bf16x8_t bq = *(const bf16x8_t*)(smem + WQ_OFF + (ot * 16 + c) * 80 + q4 * 16);
    bf16x8_t bk = *(const bf16x8_t*)(smem + WK_OFF + (ot * 16 + c) * 80 + q4 * 16);
#pragma unroll
    for (int sub = 0; sub < 2; ++sub) {
      qacc[sub][ot] = __builtin_amdgcn_mfma_f32_16x16x32_bf16(a_xl[sub], bq, zero, 0, 0, 0);
      kacc[sub][ot] = __builtin_amdgcn_mfma_f32_16x16x32_bf16(a_xr[sub], bk, zero, 0, 0, 0);
    }
  }
  {
    const float scale = 0.17677669529663687f;  // 1/sqrt(32)
    unsigned short* qsp = (unsigned short*)(smem + QS_OFF);
    unsigned short* ksp = (unsigned short*)(smem + KS_OFF);
#pragma unroll
    for (int sub = 0; sub < 2; ++sub)
#pragma unroll
      for (int r = 0; r < 4; ++r) {
        int w = wbase + sub * 16 + q4 * 4 + r;
        float2 sc = rope[w * 16 + c];
        float sn = sc.x, cs = sc.y;
        float q0 = qacc[sub][0][r], q1 = qacc[sub][1][r];
        qsp[w * 40 + c]      = f2bbt((q0 * cs - q1 * sn) * scale);
        qsp[w * 40 + c + 16] = f2bbt((q1 * cs + q0 * sn) * scale);
        float k0 = kacc[sub][0][r], k1 = kacc[sub][1][r];
        ksp[w * 40 + c]      = f2bbt(k0 * cs - k1 * sn);
        ksp[w * 40 + c + 16] = f2bbt(k1 * cs + k0 * sn);
      }
  }
  __syncthreads();  // B2

  // ---- V^T projection; fp8 x16, permuted-k ----
  {
    f32x4_t vacc[2][2];
#pragma unroll
    for (int dt = 0; dt < 2; ++dt) {
      bf16x8_t awv = *(const bf16x8_t*)(smem + WV_OFF + (dt * 16 + c) * 80 + q4 * 16);
#pragma unroll
      for (int sub = 0; sub < 2; ++sub)
        vacc[dt][sub] = __builtin_amdgcn_mfma_f32_16x16x32_bf16(awv, a_xr[sub], zero, 0, 0, 0);
    }
    unsigned char* vtp = (unsigned char*)(smem + VT_OFF);
#pragma unroll
    for (int dt = 0; dt < 2; ++dt)
#pragma unroll
      for (int r = 0; r < 4; ++r) {
        int d = dt * 16 + q4 * 4 + r;
        int u = __builtin_amdgcn_cvt_pk_fp8_f32(vacc[dt][0][r] * 16.0f,
                                                vacc[dt][1][r] * 16.0f, 0, false);
        *(unsigned short*)(vtp + d * 136 + c * 8 + wid * 2) = (unsigned short)(u & 0xffff);
      }
  }

  // ---- S = Q' K'^T (MFMA) ----
  bf16x8_t aq0 = *(const bf16x8_t*)(smem + QS_OFF + (wbase + c) * 80 + q4 * 16);
  bf16x8_t aq1 = *(const bf16x8_t*)(smem + QS_OFF + (wbase + 16 + c) * 80 + q4 * 16);
  f32x4_t sac[2][8];
#pragma unroll
  for (int kt = 0; kt < 8; ++kt) {
    bf16x8_t bk = *(const bf16x8_t*)(smem + KS_OFF + (kt * 16 + c) * 80 + q4 * 16);
    sac[0][kt] = __builtin_amdgcn_mfma_f32_16x16x32_bf16(aq0, bk, zero, 0, 0, 0);
    sac[1][kt] = __builtin_amdgcn_mfma_f32_16x16x32_bf16(aq1, bk, zero, 0, 0, 0);
  }

  // ---- softpick ----
  float dinv_[2][4];
#pragma unroll
  for (int sub = 0; sub < 2; ++sub)
#pragma unroll
    for (int r = 0; r < 4; ++r) {
      float m = sac[sub][0][r];
#pragma unroll
      for (int kt = 1; kt < 8; ++kt) m = fmaxf(m, sac[sub][kt][r]);
      m = fmaxf(m, __shfl_xor(m, 1));
      m = fmaxf(m, __shfl_xor(m, 2));
      m = fmaxf(m, __shfl_xor(m, 4));
      m = fmaxf(m, __shfl_xor(m, 8));
      float em = __expf(-m);
      float ss = 0.f;
#pragma unroll
      for (int kt = 0; kt < 8; ++kt) {
        float e = __expf(sac[sub][kt][r] - m) - em;
        sac[sub][kt][r] = fmaxf(e, 0.f);
        ss += fabsf(e);
      }
      ss += __shfl_xor(ss, 1);
      ss += __shfl_xor(ss, 2);
      ss += __shfl_xor(ss, 4);
      ss += __shfl_xor(ss, 8);
      dinv_[sub][r] = 1.0f / (ss + 1e-6f);
    }
  __syncthreads();  // B3

  // ---- write P fp8 (x16), permuted-k ----
  {
    unsigned char* pp = (unsigned char*)(smem + P_OFF);
#pragma unroll
    for (int sub = 0; sub < 2; ++sub)
#pragma unroll
      for (int r = 0; r < 4; ++r) {
        int w = wbase + sub * 16 + q4 * 4 + r;
        float s16 = dinv_[sub][r] * 16.0f;
        int u0 = __builtin_amdgcn_cvt_pk_fp8_f32(sac[sub][0][r] * s16, sac[sub][1][r] * s16, 0, false);
        u0 = __builtin_amdgcn_cvt_pk_fp8_f32(sac[sub][2][r] * s16, sac[sub][3][r] * s16, u0, true);
        int u1 = __builtin_amdgcn_cvt_pk_fp8_f32(sac[sub][4][r] * s16, sac[sub][5][r] * s16, 0, false);
        u1 = __builtin_amdgcn_cvt_pk_fp8_f32(sac[sub][6][r] * s16, sac[sub][7][r] * s16, u1, true);
        uint2 u; u.x = (unsigned)u0; u.y = (unsigned)u1;
        *(uint2*)(pp + w * 136 + c * 8) = u;
      }
  }

  // ---- PV (fp8 MFMA) ----
  f32x4_t oacc[2][2] = {{zero, zero}, {zero, zero}};
#pragma unroll
  for (int ks = 0; ks < 4; ++ks) {
    long ap0 = *(const long*)(smem + P_OFF + (wbase + c) * 136 + ks * 32 + q4 * 8);
    long ap1 = *(const long*)(smem + P_OFF + (wbase + 16 + c) * 136 + ks * 32 + q4 * 8);
    long bv0 = *(const long*)(smem + VT_OFF + (c) * 136 + ks * 32 + q4 * 8);
    long bv1 = *(const long*)(smem + VT_OFF + (16 + c) * 136 + ks * 32 + q4 * 8);
    oacc[0][0] = __builtin_amdgcn_mfma_f32_16x16x32_fp8_fp8(ap0, bv0, oacc[0][0], 0, 0, 0);
    oacc[0][1] = __builtin_amdgcn_mfma_f32_16x16x32_fp8_fp8(ap0, bv1, oacc[0][1], 0, 0, 0);
    oacc[1][0] = __builtin_amdgcn_mfma_f32_16x16x32_fp8_fp8(ap1, bv0, oacc[1][0], 0, 0, 0);
    oacc[1][1] = __builtin_amdgcn_mfma_f32_16x16x32_fp8_fp8(ap1, bv1, oacc[1][1], 0, 0, 0);
  }
  // ---- epilogue: unscale 1/256, truncating bf16 store ----
  {
    __hip_bfloat16* ob = att_out + ((size_t)(b * cH + h) * cW) * cC + g * cHS;
#pragma unroll
    for (int sub = 0; sub < 2; ++sub)
#pragma unroll
      for (int dt = 0; dt < 2; ++dt)
#pragma unroll
        for (int r = 0; r < 4; ++r) {
          int w = wbase + sub * 16 + q4 * 4 + r;
          *(unsigned short*)&ob[(size_t)w * cC + dt * 16 + c] =
              f2bbt(oacc[sub][dt][r] * 0.00390625f);
        }
  }
}

// ---------------- ffn1 GEMM: hidden(fp8,x64) = gelu(x1 @ w1T^T + b1), sigmoid-gelu ----------
__global__ __launch_bounds__(256) void ffn1_gemm(
    const __hip_bfloat16* __restrict__ A, const __hip_bfloat16* __restrict__ Bt,
    const float* __restrict__ bias, unsigned char* __restrict__ outb)
{
  constexpr int K = 256, N = 1024;
  __shared__ __align__(16) char smem[49152];  // 3 x (As 8KB + Bs 8KB)
  const int t = threadIdx.x;
  const int id = blockIdx.x;
  const int slot = id >> 3;
  const int by = (id & 7) * 128 + (slot >> 3);
  const int bx = slot & 7;
  const int m0 = by * 128, n0 = bx * 128;
  const int lane = t & 63, wid = t >> 6;
  const int r16 = lane & 15, kq = lane >> 4;
  const int wr = (wid >> 1) * 64, wc = (wid & 1) * 64;

  f32x4_t acc[4][4];
#pragma unroll
  for (int fi = 0; fi < 4; ++fi)
#pragma unroll
    for (int fj = 0; fj < 4; ++fj) acc[fi][fj] = {0.f, 0.f, 0.f, 0.f};

  auto stage = [&](int buf, int k0) {
    char* As = smem + buf * 16384;
    char* Bs = As + 8192;
#pragma unroll
    for (int i = 0; i < 2; ++i) {
      int chunk = i * 4 + wid;
      int row = chunk * 16 + (lane >> 2);
      int sw = (((lane & 3) ^ ((row >> 1) & 3))) * 8;
      GLOAD_LDS16(A  + (size_t)(m0 + row) * K + k0 + sw, As + chunk * 1024);
      GLOAD_LDS16(Bt + (size_t)(n0 + row) * K + k0 + sw, Bs + chunk * 1024);
    }
  };

  constexpr int NK = K >> 5;  // 8
  stage(0, 0);
  stage(1, 32);
  for (int tt = 0; tt < NK; ++tt) {
    if (tt + 2 < NK) {
      stage((tt + 2) % 3, (tt + 2) << 5);
      asm volatile("s_waitcnt vmcnt(8)" ::: "memory");
    } else if (tt + 1 < NK) {
      asm volatile("s_waitcnt vmcnt(4)" ::: "memory");
    } else {
      asm volatile("s_waitcnt vmcnt(0)" ::: "memory");
    }
    __builtin_amdgcn_s_barrier();
    __builtin_amdgcn_sched_barrier(0);  // pin ds_reads after the rendezvous (rule #18)
    char* As = smem + (tt % 3) * 16384;
    char* Bs = As + 8192;
    bf16x8_t af[4], bf[4];
#pragma unroll
    for (int fi = 0; fi < 4; ++fi) {
      int rr = wr + fi * 16 + r16;
      af[fi] = *(const bf16x8_t*)(As + rr * 64 + ((kq ^ ((rr >> 1) & 3)) * 16));
    }
#pragma unroll
    for (int fj = 0; fj < 4; ++fj) {
      int rr = wc + fj * 16 + r16;
      bf[fj] = *(const bf16x8_t*)(Bs + rr * 64 + ((kq ^ ((rr >> 1) & 3)) * 16));
    }
#pragma unroll
    for (int fi = 0; fi < 4; ++fi)
#pragma unroll
      for (int fj = 0; fj < 4; ++fj)
        acc[fi][fj] = __builtin_amdgcn_mfma_f32_16x16x32_bf16(af[fi], bf[fj], acc[fi][fj], 0, 0, 0);
    __builtin_amdgcn_sched_barrier(0);
    __builtin_amdgcn_s_barrier();       // WAR
  }

  // ---- epilogue: bias + sigmoid-gelu, x64 scale, fp8 packed permuted stores ----
  float bv[4];
#pragma unroll
  for (int fj = 0; fj < 4; ++fj) bv[fj] = bias[n0 + wc + fj * 16 + r16];
  unsigned char* obase = outb + (size_t)(m0 + wr + kq * 4) * N + n0 + wc + r16 * 4;
#pragma unroll
  for (int fi = 0; fi < 4; ++fi)
#pragma unroll
    for (int r = 0; r < 4; ++r) {
      float v0 = gelu_sig(acc[fi][0][r] + bv[0]) * 64.0f;
      float v1 = gelu_sig(acc[fi][1][r] + bv[1]) * 64.0f;
      float v2 = gelu_sig(acc[fi][2][r] + bv[2]) * 64.0f;
      float v3 = gelu_sig(acc[fi][3][r] + bv[3]) * 64.0f;
      int u = __builtin_amdgcn_cvt_pk_fp8_f32(v0, v1, 0, false);
      u = __builtin_amdgcn_cvt_pk_fp8_f32(v2, v3, u, true);
      *(unsigned int*)(obase + (size_t)(fi * 16 + r) * N) = (unsigned)u;
    }
}

// ---------------- proj GEMM + left residual + LN1 -> bf16 x1 (truncating output) ----------------
__global__ __launch_bounds__(256, 2) void proj_gemm_ln(
    const __hip_bfloat16* __restrict__ A, const __hip_bfloat16* __restrict__ Bt,
    const float* __restrict__ bias, const float* __restrict__ leftres,
    const float* __restrict__ g, const float* __restrict__ be,
    __hip_bfloat16* __restrict__ outp)
{
  constexpr int KK = 256;
  __shared__ __align__(16) char smem[73728];  // 3 x (As 8KB + Bs 16KB)
  const int t = threadIdx.x, lane = t & 63, wid = t >> 6;
  const int c = lane & 15, q4 = lane >> 4;
  const int m0 = blockIdx.x * 128;
  const int wr = wid * 32;
  const f32x4_t zero = {0.f, 0.f, 0.f, 0.f};

  f32x4_t acc[2][16];
#pragma unroll
  for (int fi = 0; fi < 2; ++fi)
#pragma unroll
    for (int fj = 0; fj < 16; ++fj) acc[fi][fj] = zero;

  auto stage = [&](int buf, int k0) {
    char* As = smem + buf * 24576;
    char* Bs = As + 8192;
#pragma unroll
    for (int i = 0; i < 2; ++i) {
      int chunk = (wid * 2 + i);
      int row = chunk * 16 + (lane >> 2);
      int sw = (((lane & 3) ^ ((row >> 1) & 3))) * 8;
      GLOAD_LDS16(A + (size_t)(m0 + row) * KK + k0 + sw, As + chunk * 1024);
    }
#pragma unroll
    for (int i = 0; i < 4; ++i) {
      int chunk = (wid * 4 + i);
      int row = chunk * 16 + (lane >> 2);
      int sw = (((lane & 3) ^ ((row >> 1) & 3))) * 8;
      GLOAD_LDS16(Bt + (size_t)row * KK + k0 + sw, Bs + chunk * 1024);
    }
  };

  constexpr int NK = KK >> 5;
  stage(0, 0);
  stage(1, 32);
  for (int tt = 0; tt < NK; ++tt) {
    if (tt + 2 < NK) {
      stage((tt + 2) % 3, (tt + 2) << 5);
      asm volatile("s_waitcnt vmcnt(12)" ::: "memory");
    } else if (tt + 1 < NK) {
      asm volatile("s_waitcnt vmcnt(6)" ::: "memory");
    } else {
      asm volatile("s_waitcnt vmcnt(0)" ::: "memory");
    }
    __builtin_amdgcn_s_barrier();
    __builtin_amdgcn_sched_barrier(0);
    char* As = smem + (tt % 3) * 24576;
    char* Bs = As + 8192;
    int ra0 = wr + c, ra1 = wr + 16 + c;
    bf16x8_t af0 = *(const bf16x8_t*)(As + ra0 * 64 + ((q4 ^ ((ra0 >> 1) & 3)) * 16));
    bf16x8_t af1 = *(const bf16x8_t*)(As + ra1 * 64 + ((q4 ^ ((ra1 >> 1) & 3)) * 16));
#pragma unroll
    for (int fj = 0; fj < 16; ++fj) {
      int rb = fj * 16 + c;
      bf16x8_t bf = *(const bf16x8_t*)(Bs + rb * 64 + ((q4 ^ ((rb >> 1) & 3)) * 16));
      acc[0][fj] = __builtin_amdgcn_mfma_f32_16x16x32_bf16(af0, bf, acc[0][fj], 0, 0, 0);
      acc[1][fj] = __builtin_amdgcn_mfma_f32_16x16x32_bf16(af1, bf, acc[1][fj], 0, 0, 0);
    }
    __builtin_amdgcn_sched_barrier(0);
    __builtin_amdgcn_s_barrier();
  }

  // ---- epilogue: bias + left^T residual ----
  {
    const int b_ = m0 >> 15, h_ = (m0 >> 7) & 255;
#pragma unroll
    for (int fj = 0; fj < 16; ++fj) {
      int n = fj * 16 + c;
      float bv = bias[n];
#pragma unroll
      for (int fi = 0; fi < 2; ++fi) {
        int w0 = wr + fi * 16 + q4 * 4;
        float4 lr = *(const float4*)(leftres + (((size_t)b_ * 256 + n) * 256 + h_) * 128 + w0);
        float la[4] = {lr.x, lr.y, lr.z, lr.w};
#pragma unroll
        for (int r = 0; r < 4; ++r) acc[fi][fj][r] += bv + la[r];
      }
    }
  }

  // ---- LN1 in-register ----
  float mu[2][4], rs[2][4];
#pragma unroll
  for (int fi = 0; fi < 2; ++fi)
#pragma unroll
    for (int r = 0; r < 4; ++r) {
      float s = 0.f;
#pragma unroll
      for (int fj = 0; fj < 16; ++fj) s += acc[fi][fj][r];
      s += __shfl_xor(s, 1); s += __shfl_xor(s, 2); s += __shfl_xor(s, 4); s += __shfl_xor(s, 8);
      float m_ = s * (1.0f / 256.0f);
      float sq = 0.f;
#pragma unroll
      for (int fj = 0; fj < 16; ++fj) { float d = acc[fi][fj][r] - m_; sq += d * d; }
      sq += __shfl_xor(sq, 1); sq += __shfl_xor(sq, 2); sq += __shfl_xor(sq, 4); sq += __shfl_xor(sq, 8);
      mu[fi][r] = m_;
      rs[fi][r] = rsqrtf(sq * (1.0f / 256.0f) + 1e-5f);
    }
#pragma unroll
  for (int fj = 0; fj < 16; ++fj) {
    int n = fj * 16 + c;
    float gv = g[n], bev = be[n];
#pragma unroll
    for (int fi = 0; fi < 2; ++fi)
#pragma unroll
      for (int r = 0; r < 4; ++r) {
        int row = wr + fi * 16 + q4 * 4 + r;
        *(unsigned short*)&outp[(size_t)(m0 + row) * 256 + n] =
            f2bbt((acc[fi][fj][r] - mu[fi][r]) * rs[fi][r] * gv + bev);
      }
  }
}

// ---------------- ffn2 (fp8 x fp8) + b2 + x1 residual + LN2 -> fp32 d_out ----------------
__global__ __launch_bounds__(256, 2) void ffn2_ln(
    const unsigned char* __restrict__ A, const unsigned char* __restrict__ Bt,
    const float* __restrict__ bias, const __hip_bfloat16* __restrict__ resbf,
    const float* __restrict__ g, const float* __restrict__ be,
    float* __restrict__ outp)
{
  constexpr int KK = 1024;
  __shared__ __align__(16) char smem[73728];  // 3 x (As 8KB + Bs 16KB)
  const int t = threadIdx.x, lane = t & 63, wid = t >> 6;
  const int c = lane & 15, q4 = lane >> 4;
  const int m0 = blockIdx.x * 128;
  const int wr = wid * 32;
  const f32x4_t zero = {0.f, 0.f, 0.f, 0.f};

  f32x4_t acc[2][16];
#pragma unroll
  for (int fi = 0; fi < 2; ++fi)
#pragma unroll
    for (int fj = 0; fj < 16; ++fj) acc[fi][fj] = zero;

  auto stage = [&](int buf, int k0) {
    char* As = smem + buf * 24576;
    char* Bs = As + 8192;
#pragma unroll
    for (int i = 0; i < 2; ++i) {
      int chunk = (wid * 2 + i);
      int row = chunk * 16 + (lane >> 2);
      int sw = (((lane & 3) ^ ((row >> 1) & 3))) * 16;  // 16B slots, byte units
      GLOAD_LDS16(A + (size_t)(m0 + row) * KK + k0 + sw, As + chunk * 1024);
    }
#pragma unroll
    for (int i = 0; i < 4; ++i) {
      int chunk = (wid * 4 + i);
      int row = chunk * 16 + (lane >> 2);
      int sw = (((lane & 3) ^ ((row >> 1) & 3))) * 16;
      GLOAD_LDS16(Bt + (size_t)row * KK + k0 + sw, Bs + chunk * 1024);
    }
  };

  constexpr int NK = 16;  // K-steps of 64 fp8
  stage(0, 0);
  stage(1, 64);
  const int sl = (c >> 1) & 3;
  const int koff0 = ((((q4 >> 1)) ^ sl) << 4) | ((q4 & 1) << 3);
  const int koff1 = (((2 | (q4 >> 1)) ^ sl) << 4) | ((q4 & 1) << 3);
  for (int tt = 0; tt < NK; ++tt) {
    if (tt + 2 < NK) {
      stage((tt + 2) % 3, (tt + 2) << 6);
      asm volatile("s_waitcnt vmcnt(12)" ::: "memory");
    } else if (tt + 1 < NK) {
      asm volatile("s_waitcnt vmcnt(6)" ::: "memory");
    } else {
      asm volatile("s_waitcnt vmcnt(0)" ::: "memory");
    }
    __builtin_amdgcn_s_barrier();
    __builtin_amdgcn_sched_barrier(0);
    char* As = smem + (tt % 3) * 24576;
    char* Bs = As + 8192;
    const char* arow0 = As + (wr + c) * 64;
    const char* arow1 = As + (wr + 16 + c) * 64;
    long a00 = *(const long*)(arow0 + koff0);
    long a01 = *(const long*)(arow0 + koff1);
    long a10 = *(const long*)(arow1 + koff0);
    long a11 = *(const long*)(arow1 + koff1);
#pragma unroll
    for (int fj = 0; fj < 16; ++fj) {
      const char* brow = Bs + (fj * 16 + c) * 64;
      long b0 = *(const long*)(brow + koff0);
      long b1 = *(const long*)(brow + koff1);
      acc[0][fj] = __builtin_amdgcn_mfma_f32_16x16x32_fp8_fp8(a00, b0, acc[0][fj], 0, 0, 0);
      acc[0][fj] = __builtin_amdgcn_mfma_f32_16x16x32_fp8_fp8(a01, b1, acc[0][fj], 0, 0, 0);
      acc[1][fj] = __builtin_amdgcn_mfma_f32_16x16x32_fp8_fp8(a10, b0, acc[1][fj], 0, 0, 0);
      acc[1][fj] = __builtin_amdgcn_mfma_f32_16x16x32_fp8_fp8(a11, b1, acc[1][fj], 0, 0, 0);
    }
    __builtin_amdgcn_sched_barrier(0);
    __builtin_amdgcn_s_barrier();
  }

  // ---- epilogue: unscale (2^-12) + b2 + x1 residual ----
#pragma unroll
  for (int fj = 0; fj < 16; ++fj) {
    int n = fj * 16 + c;
    float bv = bias[n];
#pragma unroll
    for (int fi = 0; fi < 2; ++fi)
#pragma unroll
      for (int r = 0; r < 4; ++r) {
        int row = wr + fi * 16 + q4 * 4 + r;
        acc[fi][fj][r] = acc[fi][fj][r] * 0.000244140625f + bv +
                         __bfloat162float(resbf[(size_t)(m0 + row) * 256 + n]);
      }
  }

  // ---- LN2 in-register ----
  float mu[2][4], rs[2][4];
#pragma unroll
  for (int fi = 0; fi < 2; ++fi)
#pragma unroll
    for (int r = 0; r < 4; ++r) {
      float s = 0.f;
#pragma unroll
      for (int fj = 0; fj < 16; ++fj) s += acc[fi][fj][r];
      s += __shfl_xor(s, 1); s += __shfl_xor(s, 2); s += __shfl_xor(s, 4); s += __shfl_xor(s, 8);
      float m_ = s * (1.0f / 256.0f);
      float sq = 0.f;
#pragma unroll
      for (int fj = 0; fj < 16; ++fj) { float d = acc[fi][fj][r] - m_; sq += d * d; }
      sq += __shfl_xor(sq, 1); sq += __shfl_xor(sq, 2); sq += __shfl_xor(sq, 4); sq += __shfl_xor(sq, 8);
      mu[fi][r] = m_;
      rs[fi][r] = rsqrtf(sq * (1.0f / 256.0f) + 1e-5f);
    }
#pragma unroll
  for (int fj = 0; fj < 16; ++fj) {
    int n = fj * 16 + c;
    float gv = g[n], bev = be[n];
#pragma unroll
    for (int fi = 0; fi < 2; ++fi)
#pragma unroll
      for (int r = 0; r < 4; ++r) {
        int row = wr + fi * 16 + q4 * 4 + r;
        outp[(size_t)(m0 + row) * 256 + n] =
            (acc[fi][fj][r] - mu[fi][r]) * rs[fi][r] * gv + bev;
      }
  }
}

extern "C" void kernel_launch(void* const* d_in, const int* in_sizes, int n_in,
                              void* d_out, int out_size, void* d_ws, size_t ws_size,
                              hipStream_t stream) {
  const float* left   = (const float*)d_in[0];
  const float* right  = (const float*)d_in[1];
  const float* qw     = (const float*)d_in[2];
  const float* kw     = (const float*)d_in[3];
  const float* vw     = (const float*)d_in[4];
  const float* proj_w = (const float*)d_in[5];
  const float* proj_b = (const float*)d_in[6];
  const float* ln1_g  = (const float*)d_in[7];
  const float* ln1_b  = (const float*)d_in[8];
  const float* ln2_g  = (const float*)d_in[9];
  const float* ln2_b  = (const float*)d_in[10];
  const float* w1     = (const float*)d_in[11];
  const float* b1     = (const float*)d_in[12];
  const float* w2     = (const float*)d_in[13];
  const float* b2     = (const float*)d_in[14];

  char* ws = (char*)d_ws;
  __hip_bfloat16* att_out = (__hip_bfloat16*)ws;                 // [M,256]  bf16 [0, 67MB)
  __hip_bfloat16* x1      = (__hip_bfloat16*)(ws + 67108864);    // [M,256]  bf16 [67,134MB)
  unsigned char*  hidden  = (unsigned char*)(ws + 134217728);    // [M,1024] fp8  [134,268MB)
  float2*         rope    = (float2*)(ws + 301989888);           // 16KB
  __hip_bfloat16* pwT     = (__hip_bfloat16*)(ws + 402653184);   // [256][256] bf16
  __hip_bfloat16* w1T     = pwT + 65536;                         // [1024][256] bf16
  unsigned char*  w2T     = (unsigned char*)(w1T + 262144);      // [256][1024] fp8, k-perm, x64

  transpose_bf16<<<256, 256, 0, stream>>>(proj_w, pwT, 256, 256);
  transpose_bf16<<<1024, 256, 0, stream>>>(w1, w1T, 256, 1024);
  transpose_perm_fp8<<<1024, 256, 0, stream>>>(w2, w2T, 1024, 256);
  rope_init<<<8, 256, 0, stream>>>(rope);

  attn_mfma<<<cB * cH * cHN, 256, 0, stream>>>(left, right, qw, kw, vw, rope, att_out);

  // x1 = LN1(att_out @ proj_w + proj_b + left^T)
  proj_gemm_ln<<<cM / 128, 256, 0, stream>>>(att_out, pwT, proj_b, left, ln1_g, ln1_b, x1);
  // hidden(fp8) = gelu(x1 @ w1 + b1) * 64   (sigmoid-gelu epilogue)
  ffn1_gemm<<<8192, 256, 0, stream>>>(x1, w1T, b1, hidden);
  // out = LN2(hidden @ w2 / 4096 + b2 + x1)
  ffn2_ln<<<cM / 128, 256, 0, stream>>>(hidden, w2T, b2, x1, ln2_g, ln2_b, (float*)d_out);
}